// Round 8
// baseline (300.606 us; speedup 1.0000x reference)
//
#include <hip/hip_runtime.h>
#include <hip/hip_fp16.h>
#include <cstdint>
#include <cstddef>

#define NPB_SHIFT 8                      // 256 dst-nodes per bucket
#define NPB (1 << NPB_SHIFT)
#define CHUNK 4096                       // edges per partition block
#define BCAP 6144                        // slots per bucket slab (lambda=4096, +32 sigma)
// nbuck = ceil(N/256) must be <= 512 (N <= 131072) for the LDS arrays below.

typedef _Float16 half8_t __attribute__((ext_vector_type(8)));
typedef _Float16 half4_t __attribute__((ext_vector_type(4)));
typedef _Float16 half2_t __attribute__((ext_vector_type(2)));
typedef float floatx4 __attribute__((ext_vector_type(4)));

#define H2(u) __builtin_bit_cast(half2_t, (u))

// ---------------- graph preprocessing ----------------
// Round-4 proven pipeline, minus csr_build's count pass: per-node degrees are
// now accumulated in k_partition via global atomics into dcount[] (dense
// 400KB, cache-resident -- NOT the round-5 trap, which was scattered
// partial-line 4B *stores* to a 25MB slab).

__global__ __launch_bounds__(256) void k_partition(const int* __restrict__ src,
                                                   const int* __restrict__ dst,
                                                   int* __restrict__ bfill,
                                                   int* __restrict__ dcount,
                                                   unsigned* __restrict__ tmp,
                                                   int E, int nbuck) {
  __shared__ int cnt[512];
  __shared__ int lbase[512];
  __shared__ int gdelta[512];
  __shared__ int cur[512];
  __shared__ int ps[256];
  __shared__ unsigned sval[CHUNK];
  __shared__ unsigned short sbid[CHUNK];
  int tid = threadIdx.x;
  int cbase = blockIdx.x * CHUNK;
  for (int i = tid; i < 512; i += 256) cnt[i] = 0;
  __syncthreads();
  int s[16], d[16];
  bool valid[16];
#pragma unroll
  for (int u = 0; u < 16; ++u) {
    int e = cbase + u * 256 + tid;
    valid[u] = e < E;
    s[u] = valid[u] ? src[e] : 0;
    d[u] = valid[u] ? dst[e] : 0;
    if (valid[u]) {
      atomicAdd(&cnt[d[u] >> NPB_SHIFT], 1);
      atomicAdd(&dcount[d[u]], 1);       // per-node degree (dense, cached)
    }
  }
  __syncthreads();
  int c0 = cnt[2 * tid], c1 = cnt[2 * tid + 1];
  int p = c0 + c1;
  ps[tid] = p;
  __syncthreads();
  for (int off = 1; off < 256; off <<= 1) {
    int t = (tid >= off) ? ps[tid - off] : 0;
    __syncthreads();
    ps[tid] += t;
    __syncthreads();
  }
  int ep = ps[tid] - p;                  // exclusive over pairs
  lbase[2 * tid] = ep;
  lbase[2 * tid + 1] = ep + c0;
  __syncthreads();
  for (int i = tid; i < 512; i += 256) {
    cur[i] = lbase[i];
    if (cnt[i]) gdelta[i] = atomicAdd(&bfill[i], cnt[i]) - lbase[i];
  }
  __syncthreads();
#pragma unroll
  for (int u = 0; u < 16; ++u) {
    if (valid[u]) {
      int b = d[u] >> NPB_SHIFT;
      int r = atomicAdd(&cur[b], 1);
      sval[r] = ((unsigned)s[u] << NPB_SHIFT) | (unsigned)(d[u] & (NPB - 1));
      sbid[r] = (unsigned short)b;
    }
  }
  __syncthreads();
  int nv = min(CHUNK, E - cbase);
  for (int i = tid; i < nv; i += 256) {
    unsigned v = sval[i];
    int b = sbid[i];
    tmp[(size_t)b * BCAP + (gdelta[b] + i)] = v;
  }
}

// per bucket: scan bucket counts in-LDS -> dense base; degrees come from
// dcount (no tmp count pass); scan -> dinv + dense offsets; scatter ssrc.
__global__ __launch_bounds__(256) void k_csr_build(const unsigned* __restrict__ tmp,
                                                   const int* __restrict__ bfill,
                                                   const int* __restrict__ dcount,
                                                   float* __restrict__ dinv,
                                                   int* __restrict__ offset,
                                                   int* __restrict__ ssrc,
                                                   int N, int E, int nbuck) {
  __shared__ int scan[NPB];
  __shared__ int fillL[NPB];
  __shared__ int bs[512];
  __shared__ int ps[256];
  int b = blockIdx.x, tid = threadIdx.x;
  int nbase = b << NPB_SHIFT;
  int nloc = min(NPB, N - nbase);
  bs[tid] = (tid < nbuck) ? bfill[tid] : 0;
  bs[tid + 256] = (tid + 256 < nbuck) ? bfill[tid + 256] : 0;
  __syncthreads();
  int c0 = bs[2 * tid], c1 = bs[2 * tid + 1];
  int pp = c0 + c1;
  ps[tid] = pp;
  __syncthreads();
  for (int off = 1; off < 256; off <<= 1) {
    int t = (tid >= off) ? ps[tid - off] : 0;
    __syncthreads();
    ps[tid] += t;
    __syncthreads();
  }
  int ep = ps[tid] - pp;
  bs[2 * tid] = ep;
  bs[2 * tid + 1] = ep + c0;
  __syncthreads();
  int ebeg = bs[b];                    // dense base of this bucket
  int cntB = bfill[b];
  int sbeg = b * BCAP;
  int send = sbeg + cntB;
  int v = (tid < nloc) ? dcount[nbase + tid] : 0;
  scan[tid] = v;
  __syncthreads();
  for (int off = 1; off < NPB; off <<= 1) {
    int t = (tid >= off) ? scan[tid - off] : 0;
    __syncthreads();
    scan[tid] += t;
    __syncthreads();
  }
  int myoff = ebeg + scan[tid] - v;
  fillL[tid] = myoff;
  if (tid < nloc) {
    offset[nbase + tid] = myoff;
    dinv[nbase + tid] = rsqrtf((float)(v + 1));   // +1 self-loop
  }
  if (b == nbuck - 1 && tid == NPB - 1) offset[N] = ebeg + scan[tid];   // == E
  __syncthreads();
  int j = sbeg + tid;
  for (; j + 3 * 256 < send; j += 4 * 256) {
    unsigned p[4];
#pragma unroll
    for (int u = 0; u < 4; ++u) p[u] = tmp[j + u * 256];
#pragma unroll
    for (int u = 0; u < 4; ++u) {
      int pos = atomicAdd(&fillL[p[u] & (NPB - 1)], 1);
      ssrc[pos] = (int)(p[u] >> NPB_SHIFT);
    }
  }
  for (; j < send; j += 256) {
    unsigned p = tmp[j];
    int pos = atomicAdd(&fillL[p & (NPB - 1)], 1);
    ssrc[pos] = (int)(p >> NPB_SHIFT);
  }
}

// ---------------- dense layers: MFMA 16x16x32 f16, output scaled by dinv ------
// Writes g[node] = dinv[node] * (x @ W)[node] as fp16, row stride OS.
// Store guard is colBase < OS (not COLS): when OS > COLS the pad columns get
// clamped-weight garbage (finite, never read by the masked agg) -- this keeps
// every written line FULL, avoiding partial-line writebacks (round-5 lesson).
template <int K, int COLS, int MT, int KC, int OS, typename XT>
__global__ __launch_bounds__(256) void k_gemm_mfma(const XT* __restrict__ x,
                                                   const float* __restrict__ W,
                                                   const float* __restrict__ dinv,
                                                   _Float16* __restrict__ out, int n) {
  int lane = threadIdx.x & 63;
  int quad = lane >> 4;
  int l15 = lane & 15;
  int gwave = (blockIdx.x * blockDim.x + threadIdx.x) >> 6;
  int nwave = (gridDim.x * blockDim.x) >> 6;
  int ntiles = (n + 15) >> 4;

  half8_t afrag[MT][KC];
#pragma unroll
  for (int m = 0; m < MT; ++m) {
    int colw = m * 16 + l15;
    if (colw > COLS - 1) colw = COLS - 1;
#pragma unroll
    for (int c = 0; c < KC; ++c) {
#pragma unroll
      for (int j = 0; j < 8; ++j) {
        int kk = c * 32 + quad * 8 + j;
        afrag[m][c][j] = (_Float16)W[kk * COLS + colw];
      }
    }
  }

  for (int tile = gwave; tile < ntiles; tile += nwave) {
    int node0 = tile << 4;
    int nodeB = node0 + l15;
    int nodeC = nodeB < n ? nodeB : n - 1;
    const XT* xr = x + (size_t)nodeC * K;
    float dv = dinv[nodeC];
    half8_t bfrag[KC];
#pragma unroll
    for (int c = 0; c < KC; ++c) {
      if constexpr (sizeof(XT) == 4) {
        float4 lo = *(const float4*)(xr + c * 32 + quad * 8);
        float4 hi = *(const float4*)(xr + c * 32 + quad * 8 + 4);
        bfrag[c][0] = (_Float16)lo.x; bfrag[c][1] = (_Float16)lo.y;
        bfrag[c][2] = (_Float16)lo.z; bfrag[c][3] = (_Float16)lo.w;
        bfrag[c][4] = (_Float16)hi.x; bfrag[c][5] = (_Float16)hi.y;
        bfrag[c][6] = (_Float16)hi.z; bfrag[c][7] = (_Float16)hi.w;
      } else {
        bfrag[c] = *(const half8_t*)(xr + c * 32 + quad * 8);
      }
    }
    floatx4 acc[MT];
#pragma unroll
    for (int m = 0; m < MT; ++m) acc[m] = (floatx4){0.f, 0.f, 0.f, 0.f};
#pragma unroll
    for (int c = 0; c < KC; ++c)
#pragma unroll
      for (int m = 0; m < MT; ++m)
        acc[m] = __builtin_amdgcn_mfma_f32_16x16x32_f16(afrag[m][c], bfrag[c], acc[m], 0, 0, 0);

    if (nodeB < n) {
#pragma unroll
      for (int m = 0; m < MT; ++m) {
        int colBase = m * 16 + quad * 4;
        if (colBase < OS) {
          half4_t hv = {(_Float16)(acc[m][0] * dv), (_Float16)(acc[m][1] * dv),
                        (_Float16)(acc[m][2] * dv), (_Float16)(acc[m][3] * dv)};
          *(half4_t*)(out + (size_t)nodeB * OS + colBase) = hv;
        }
      }
    }
  }
}

// ---------------- aggregation: 4 nodes per wave, 8 gathers in flight ----------
// At the concurrency-limited random-line fetch ceiling (~2.26 TB/s at 58%
// occupancy). Round-2: more per-wave MLP = no change (queue full). Round-7:
// fewer waves (fused epilogue, occ 58->38%) = rate 2.26->0.88 TB/s. So:
// protect occupancy (VGPR 36, no LDS); do not restructure.

__device__ __forceinline__ void addacc(half2_t* acc, uint4 r) {
  acc[0] += H2(r.x); acc[1] += H2(r.y); acc[2] += H2(r.z); acc[3] += H2(r.w);
}

template <int F, int S8, bool RELU, bool OUT_HALF>
__global__ __launch_bounds__(256) void k_agg_v4(const uint4* __restrict__ g8,
                                                const int* __restrict__ offset,
                                                const int* __restrict__ ssrc,
                                                const float* __restrict__ dinv,
                                                const float* __restrict__ bias,
                                                void* __restrict__ outp, int n) {
  constexpr int F8 = F / 8;            // used octets per row (8 or 5)
  int lane = threadIdx.x & 63;
  int g = lane >> 3;                   // edge group 0..7
  int t = lane & 7;                    // feature octet
  int wave = (blockIdx.x * blockDim.x + threadIdx.x) >> 6;
  int nb = wave * 4;                   // first node of this wave
  if (nb >= n) return;
  bool tv = t < F8;

  uint4 sv[4];
#pragma unroll
  for (int w = 0; w < 4; ++w) {
    int node = nb + w;
    int nc = node < n ? node : n - 1;
    sv[w] = (tv && g == 0 && node < n) ? g8[(size_t)nc * S8 + t]
                                       : make_uint4(0, 0, 0, 0);
  }

  int jj[4], ee[4];
  float di[4];
#pragma unroll
  for (int w = 0; w < 4; ++w) {
    int node = nb + w;
    bool nv = node < n;
    int nc = nv ? node : n - 1;
    int b0 = offset[nc];
    int b1 = offset[nc + 1];
    jj[w] = b0;
    ee[w] = nv ? b1 : b0;
    di[w] = dinv[nc];
  }

  half2_t acc[4][4];
#pragma unroll
  for (int w = 0; w < 4; ++w) {
#pragma unroll
    for (int k = 0; k < 4; ++k) acc[w][k] = H2(0u);
    addacc(acc[w], sv[w]);
  }

  for (;;) {
    bool a0[4], a1[4];
    bool any = false;
#pragma unroll
    for (int w = 0; w < 4; ++w) {
      a0[w] = jj[w] + 8 <= ee[w];
      a1[w] = jj[w] + 16 <= ee[w];
      any = any || a0[w];
    }
    if (!any) break;
    int s0[4], s1[4];
#pragma unroll
    for (int w = 0; w < 4; ++w) {
      s0[w] = a0[w] ? ssrc[jj[w] + g] : 0;
      s1[w] = a1[w] ? ssrc[jj[w] + 8 + g] : 0;
    }
    uint4 r0[4], r1[4];
#pragma unroll
    for (int w = 0; w < 4; ++w) {
      r0[w] = (a0[w] && tv) ? g8[(size_t)s0[w] * S8 + t] : make_uint4(0, 0, 0, 0);
      r1[w] = (a1[w] && tv) ? g8[(size_t)s1[w] * S8 + t] : make_uint4(0, 0, 0, 0);
    }
#pragma unroll
    for (int w = 0; w < 4; ++w) {
      addacc(acc[w], r0[w]);
      addacc(acc[w], r1[w]);
      jj[w] += a1[w] ? 16 : (a0[w] ? 8 : 0);
    }
  }

  {
    int rem[4];
    uint4 rv[4];
#pragma unroll
    for (int w = 0; w < 4; ++w) {
      rem[w] = ee[w] - jj[w];
      int gi = (g < rem[w]) ? g : (rem[w] - 1);
      int sW = rem[w] > 0 ? ssrc[jj[w] + gi] : 0;
      rv[w] = (tv && g < rem[w]) ? g8[(size_t)sW * S8 + t] : make_uint4(0, 0, 0, 0);
    }
#pragma unroll
    for (int w = 0; w < 4; ++w) addacc(acc[w], rv[w]);
  }

#pragma unroll
  for (int w = 0; w < 4; ++w) {
#pragma unroll
    for (int k = 0; k < 4; ++k) {
      int u = __builtin_bit_cast(int, acc[w][k]);
      acc[w][k] += H2((unsigned)__shfl_xor(u, 8));
      u = __builtin_bit_cast(int, acc[w][k]);
      acc[w][k] += H2((unsigned)__shfl_xor(u, 16));
      u = __builtin_bit_cast(int, acc[w][k]);
      acc[w][k] += H2((unsigned)__shfl_xor(u, 32));
    }
    int node = nb + w;
    if (node < n && lane < F8) {
      float f[8];
#pragma unroll
      for (int k = 0; k < 4; ++k) {
        f[2 * k] = (float)acc[w][k][0];
        f[2 * k + 1] = (float)acc[w][k][1];
      }
      const float* bb = bias + lane * 8;
      float o[8];
#pragma unroll
      for (int j = 0; j < 8; ++j) {
        o[j] = fmaf(f[j], di[w], bb[j]);
        if (RELU) o[j] = fmaxf(o[j], 0.f);
      }
      if (OUT_HALF) {
        _Float16* op = (_Float16*)outp + (size_t)node * F + lane * 8;
        half2_t p0 = {(_Float16)o[0], (_Float16)o[1]};
        half2_t p1 = {(_Float16)o[2], (_Float16)o[3]};
        half2_t p2 = {(_Float16)o[4], (_Float16)o[5]};
        half2_t p3 = {(_Float16)o[6], (_Float16)o[7]};
        uint4 wv;
        wv.x = __builtin_bit_cast(unsigned, p0);
        wv.y = __builtin_bit_cast(unsigned, p1);
        wv.z = __builtin_bit_cast(unsigned, p2);
        wv.w = __builtin_bit_cast(unsigned, p3);
        *(uint4*)op = wv;
      } else {
        float* op = (float*)outp + (size_t)node * F + lane * 8;
        *(float4*)op = make_float4(o[0], o[1], o[2], o[3]);
        *(float4*)(op + 4) = make_float4(o[4], o[5], o[6], o[7]);
      }
    }
  }
}

// ---------------- launch ----------------

extern "C" void kernel_launch(void* const* d_in, const int* in_sizes, int n_in,
                              void* d_out, int out_size, void* d_ws, size_t ws_size,
                              hipStream_t stream) {
  const float* x  = (const float*)d_in[0];
  const int*   ei = (const int*)d_in[1];
  const float* W1 = (const float*)d_in[2];
  const float* b1 = (const float*)d_in[3];
  const float* W2 = (const float*)d_in[4];
  const float* b2 = (const float*)d_in[5];
  float* out = (float*)d_out;

  const int F_IN = 128, HID = 64, C = 40;
  int N = in_sizes[0] / F_IN;
  int E = in_sizes[1] / 2;
  const int* src = ei;
  const int* dst = ei + E;
  int nbuck = (N + NPB - 1) >> NPB_SHIFT;   // 391 for N=100000

  char* w = (char*)d_ws;
  size_t o = 0;
  auto alloc = [&](size_t bytes) -> void* {
    void* p = w + o;
    o = (o + bytes + 255) & ~(size_t)255;
    return p;
  };
  int*      dcount = (int*)alloc((size_t)N * 4);
  int*      bfill  = (int*)alloc(512 * 4);          // contiguous after dcount
  float*    dinv   = (float*)alloc((size_t)N * 4);
  int*      offset = (int*)alloc((size_t)(N + 1) * 4);
  unsigned* tmp    = (unsigned*)alloc((size_t)nbuck * BCAP * 4);
  int*      ssrc   = (int*)alloc((size_t)E * 4);
  _Float16* g1     = (_Float16*)alloc((size_t)N * HID * 2);   // dinv*(xW1), stride 64
  _Float16* h1     = (_Float16*)alloc((size_t)N * HID * 2);   // relu layer-1 out, fp16
  _Float16* g2     = (_Float16*)alloc((size_t)N * 64 * 2);    // dinv*(h1W2), PADDED stride 64

  dim3 b256(256);

  // one memset covers dcount + bfill (adjacent in workspace)
  size_t zlen = (size_t)((char*)bfill + 512 * 4 - (char*)dcount);
  hipMemsetAsync(dcount, 0, zlen, stream);

  // partition (+ per-node degrees) -> dense CSR compaction
  k_partition<<<dim3((E + CHUNK - 1) / CHUNK), b256, 0, stream>>>(
      src, dst, bfill, dcount, tmp, E, nbuck);
  k_csr_build<<<dim3(nbuck), b256, 0, stream>>>(
      tmp, bfill, dcount, dinv, offset, ssrc, N, E, nbuck);

  // layer 1: g1 = dinv * (x @ W1);  h1 = relu(dinv*(g1[self]+sum g1[src]) + b1)
  k_gemm_mfma<128, 64, 4, 4, 64, float><<<dim3(1536), b256, 0, stream>>>(x, W1, dinv, g1, N);
  k_agg_v4<64, 8, true, true><<<dim3((N + 15) / 16), b256, 0, stream>>>(
      (const uint4*)g1, offset, ssrc, dinv, b1, h1, N);

  // layer 2: g2 = dinv * (h1 @ W2) padded to 128B rows; out = dinv*(g2[self]+sum g2[src]) + b2
  k_gemm_mfma<64, 40, 4, 2, 64, _Float16><<<dim3(1536), b256, 0, stream>>>(h1, W2, dinv, g2, N);
  k_agg_v4<40, 8, false, false><<<dim3((N + 15) / 16), b256, 0, stream>>>(
      (const uint4*)g2, offset, ssrc, dinv, b2, out, N);
}

// Round 9
// 265.511 us; speedup vs baseline: 1.1322x; 1.1322x over previous
//
#include <hip/hip_runtime.h>
#include <hip/hip_fp16.h>
#include <cstdint>
#include <cstddef>

#define NPB_SHIFT 8                      // 256 dst-nodes per bucket
#define NPB (1 << NPB_SHIFT)
#define CHUNK 4096                       // edges per partition block
#define BCAP 6144                        // slots per bucket slab (lambda=4096, +32 sigma)
// nbuck = ceil(N/256) must be <= 512 (N <= 131072) for the LDS arrays below.

typedef _Float16 half8_t __attribute__((ext_vector_type(8)));
typedef _Float16 half4_t __attribute__((ext_vector_type(4)));
typedef _Float16 half2_t __attribute__((ext_vector_type(2)));
typedef float floatx4 __attribute__((ext_vector_type(4)));

#define H2(u) __builtin_bit_cast(half2_t, (u))

// ---------------- graph preprocessing (round-4 exact, proven ~45us) ----------
// r5 lesson: no scattered partial-line stores. r8 lesson: no per-edge global
// atomic histograms (1.6M random atomics to 400KB = +30us, 35MB of cross-XCD
// line-migration writebacks). Degree counting stays in csr_build's LDS pass.

__global__ __launch_bounds__(256) void k_partition(const int* __restrict__ src,
                                                   const int* __restrict__ dst,
                                                   int* __restrict__ bfill,
                                                   unsigned* __restrict__ tmp,
                                                   int E, int nbuck) {
  __shared__ int cnt[512];
  __shared__ int lbase[512];
  __shared__ int gdelta[512];
  __shared__ int cur[512];
  __shared__ int ps[256];
  __shared__ unsigned sval[CHUNK];
  __shared__ unsigned short sbid[CHUNK];
  int tid = threadIdx.x;
  int cbase = blockIdx.x * CHUNK;
  for (int i = tid; i < 512; i += 256) cnt[i] = 0;
  __syncthreads();
  int s[16], d[16];
  bool valid[16];
#pragma unroll
  for (int u = 0; u < 16; ++u) {
    int e = cbase + u * 256 + tid;
    valid[u] = e < E;
    s[u] = valid[u] ? src[e] : 0;
    d[u] = valid[u] ? dst[e] : 0;
    if (valid[u]) atomicAdd(&cnt[d[u] >> NPB_SHIFT], 1);
  }
  __syncthreads();
  int c0 = cnt[2 * tid], c1 = cnt[2 * tid + 1];
  int p = c0 + c1;
  ps[tid] = p;
  __syncthreads();
  for (int off = 1; off < 256; off <<= 1) {
    int t = (tid >= off) ? ps[tid - off] : 0;
    __syncthreads();
    ps[tid] += t;
    __syncthreads();
  }
  int ep = ps[tid] - p;                  // exclusive over pairs
  lbase[2 * tid] = ep;
  lbase[2 * tid + 1] = ep + c0;
  __syncthreads();
  for (int i = tid; i < 512; i += 256) {
    cur[i] = lbase[i];
    if (cnt[i]) gdelta[i] = atomicAdd(&bfill[i], cnt[i]) - lbase[i];
  }
  __syncthreads();
#pragma unroll
  for (int u = 0; u < 16; ++u) {
    if (valid[u]) {
      int b = d[u] >> NPB_SHIFT;
      int r = atomicAdd(&cur[b], 1);
      sval[r] = ((unsigned)s[u] << NPB_SHIFT) | (unsigned)(d[u] & (NPB - 1));
      sbid[r] = (unsigned short)b;
    }
  }
  __syncthreads();
  int nv = min(CHUNK, E - cbase);
  for (int i = tid; i < nv; i += 256) {
    unsigned v = sval[i];
    int b = sbid[i];
    tmp[(size_t)b * BCAP + (gdelta[b] + i)] = v;
  }
}

__global__ __launch_bounds__(256) void k_csr_build(const unsigned* __restrict__ tmp,
                                                   const int* __restrict__ bfill,
                                                   float* __restrict__ dinv,
                                                   int* __restrict__ offset,
                                                   int* __restrict__ ssrc,
                                                   int N, int E, int nbuck) {
  __shared__ int cnt[NPB];
  __shared__ int scan[NPB];
  __shared__ int fillL[NPB];
  __shared__ int bs[512];
  __shared__ int ps[256];
  int b = blockIdx.x, tid = threadIdx.x;
  int nbase = b << NPB_SHIFT;
  int nloc = min(NPB, N - nbase);
  cnt[tid] = 0;
  bs[tid] = (tid < nbuck) ? bfill[tid] : 0;
  bs[tid + 256] = (tid + 256 < nbuck) ? bfill[tid + 256] : 0;
  __syncthreads();
  int c0 = bs[2 * tid], c1 = bs[2 * tid + 1];
  int pp = c0 + c1;
  ps[tid] = pp;
  __syncthreads();
  for (int off = 1; off < 256; off <<= 1) {
    int t = (tid >= off) ? ps[tid - off] : 0;
    __syncthreads();
    ps[tid] += t;
    __syncthreads();
  }
  int ep = ps[tid] - pp;
  bs[2 * tid] = ep;
  bs[2 * tid + 1] = ep + c0;
  __syncthreads();
  int ebeg = bs[b];                    // dense base of this bucket
  int cntB = bfill[b];
  int sbeg = b * BCAP;
  int send = sbeg + cntB;
  for (int j = sbeg + tid; j < send; j += 256) atomicAdd(&cnt[tmp[j] & (NPB - 1)], 1);
  __syncthreads();
  int v = cnt[tid];
  scan[tid] = v;
  __syncthreads();
  for (int off = 1; off < NPB; off <<= 1) {
    int t = (tid >= off) ? scan[tid - off] : 0;
    __syncthreads();
    scan[tid] += t;
    __syncthreads();
  }
  int myoff = ebeg + scan[tid] - v;
  fillL[tid] = myoff;
  if (tid < nloc) {
    offset[nbase + tid] = myoff;
    dinv[nbase + tid] = rsqrtf((float)(v + 1));   // +1 self-loop
  }
  if (b == nbuck - 1 && tid == NPB - 1) offset[N] = ebeg + scan[tid];   // == E
  __syncthreads();
  int j = sbeg + tid;
  for (; j + 3 * 256 < send; j += 4 * 256) {
    unsigned p[4];
#pragma unroll
    for (int u = 0; u < 4; ++u) p[u] = tmp[j + u * 256];
#pragma unroll
    for (int u = 0; u < 4; ++u) {
      int pos = atomicAdd(&fillL[p[u] & (NPB - 1)], 1);
      ssrc[pos] = (int)(p[u] >> NPB_SHIFT);
    }
  }
  for (; j < send; j += 256) {
    unsigned p = tmp[j];
    int pos = atomicAdd(&fillL[p & (NPB - 1)], 1);
    ssrc[pos] = (int)(p >> NPB_SHIFT);
  }
}

// ---------------- dense layers: MFMA 16x16x32 f16, output scaled by dinv ------
// TSTORE: write slice-major g[slice][node] (16B per node per slice) so agg can
// give each slice XCD affinity. TLOAD: read slice-major input the same way.
template <int K, int COLS, int MT, int KC, int OS, bool TLOAD, bool TSTORE, typename XT>
__global__ __launch_bounds__(256) void k_gemm_mfma(const XT* __restrict__ x,
                                                   const float* __restrict__ W,
                                                   const float* __restrict__ dinv,
                                                   _Float16* __restrict__ out, int n) {
  int lane = threadIdx.x & 63;
  int quad = lane >> 4;
  int l15 = lane & 15;
  int gwave = (blockIdx.x * blockDim.x + threadIdx.x) >> 6;
  int nwave = (gridDim.x * blockDim.x) >> 6;
  int ntiles = (n + 15) >> 4;

  half8_t afrag[MT][KC];
#pragma unroll
  for (int m = 0; m < MT; ++m) {
    int colw = m * 16 + l15;
    if (colw > COLS - 1) colw = COLS - 1;
#pragma unroll
    for (int c = 0; c < KC; ++c) {
#pragma unroll
      for (int j = 0; j < 8; ++j) {
        int kk = c * 32 + quad * 8 + j;
        afrag[m][c][j] = (_Float16)W[kk * COLS + colw];
      }
    }
  }

  for (int tile = gwave; tile < ntiles; tile += nwave) {
    int node0 = tile << 4;
    int nodeB = node0 + l15;
    int nodeC = nodeB < n ? nodeB : n - 1;
    float dv = dinv[nodeC];
    half8_t bfrag[KC];
#pragma unroll
    for (int c = 0; c < KC; ++c) {
      if constexpr (TLOAD) {
        // slice-major input: slice = 4c+quad, 16B per node
        const _Float16* hr = (const _Float16*)x +
                             ((size_t)(4 * c + quad) * n + nodeC) * 8;
        bfrag[c] = *(const half8_t*)hr;
      } else if constexpr (sizeof(XT) == 4) {
        const XT* xr = x + (size_t)nodeC * K;
        float4 lo = *(const float4*)(xr + c * 32 + quad * 8);
        float4 hi = *(const float4*)(xr + c * 32 + quad * 8 + 4);
        bfrag[c][0] = (_Float16)lo.x; bfrag[c][1] = (_Float16)lo.y;
        bfrag[c][2] = (_Float16)lo.z; bfrag[c][3] = (_Float16)lo.w;
        bfrag[c][4] = (_Float16)hi.x; bfrag[c][5] = (_Float16)hi.y;
        bfrag[c][6] = (_Float16)hi.z; bfrag[c][7] = (_Float16)hi.w;
      } else {
        const XT* xr = x + (size_t)nodeC * K;
        bfrag[c] = *(const half8_t*)(xr + c * 32 + quad * 8);
      }
    }
    floatx4 acc[MT];
#pragma unroll
    for (int m = 0; m < MT; ++m) acc[m] = (floatx4){0.f, 0.f, 0.f, 0.f};
#pragma unroll
    for (int c = 0; c < KC; ++c)
#pragma unroll
      for (int m = 0; m < MT; ++m)
        acc[m] = __builtin_amdgcn_mfma_f32_16x16x32_f16(afrag[m][c], bfrag[c], acc[m], 0, 0, 0);

    if (nodeB < n) {
#pragma unroll
      for (int m = 0; m < MT; ++m) {
        int colBase = m * 16 + quad * 4;
        if (colBase < COLS) {
          half4_t hv = {(_Float16)(acc[m][0] * dv), (_Float16)(acc[m][1] * dv),
                        (_Float16)(acc[m][2] * dv), (_Float16)(acc[m][3] * dv)};
          if constexpr (TSTORE) {
            int sl = colBase >> 3, c8 = colBase & 7;
            *(half4_t*)(out + ((size_t)sl * n + nodeB) * 8 + c8) = hv;
          } else {
            *(half4_t*)(out + (size_t)nodeB * OS + colBase) = hv;
          }
        }
      }
    }
  }
}

// ---------------- agg1: feature-sliced, XCD-affine -----------------------
// Per-XCD L2 fill was footprint x 8 (91MB measured, r2/r4): every XCD touched
// every g1 line. Slice-major g1T gives slice t a contiguous 1.6MB region;
// blocks with (blockIdx&7)==t land on XCD t (round-robin dispatch), so each
// XCD's gathers hit an L2-resident region. Mapping change = perf-neutral.
// Wave = 8 nodes x 8 edge-lanes; per lane an independent 16B-gather stream.
__device__ __forceinline__ void addacc(half2_t* acc, uint4 r) {
  acc[0] += H2(r.x); acc[1] += H2(r.y); acc[2] += H2(r.z); acc[3] += H2(r.w);
}

__global__ __launch_bounds__(256) void k_agg_slice(const uint4* __restrict__ g1t,
                                                   const int* __restrict__ offset,
                                                   const int* __restrict__ ssrc,
                                                   const float* __restrict__ dinv,
                                                   const float* __restrict__ b1,
                                                   _Float16* __restrict__ h1t,
                                                   int n) {
  int bid = blockIdx.x;
  int t = bid & 7;                      // feature slice == XCD (heuristic)
  int nblk = bid >> 3;
  int tid = threadIdx.x;
  int lane = tid & 63;
  int g = lane >> 3;                    // edge lane 0..7
  int node = nblk * 32 + (tid >> 6) * 8 + (lane & 7);
  bool nv = node < n;
  int nc = nv ? node : n - 1;
  const uint4* gt = g1t + (size_t)t * n;

  int jj = offset[nc];
  int ee = nv ? offset[nc + 1] : jj;

  half2_t acc[4];
#pragma unroll
  for (int k = 0; k < 4; ++k) acc[k] = H2(0u);
  if (g == 0 && nv) addacc(acc, gt[nc]);       // self-loop term

  int j = jj + g;
  if (j < ee) {                         // index-ahead software pipeline
    int scur = ssrc[j];
    for (;;) {
      int jn = j + 8;
      int snxt = (jn < ee) ? ssrc[jn] : 0;
      uint4 r = gt[scur];
      addacc(acc, r);
      j = jn;
      if (j >= ee) break;
      scur = snxt;
    }
  }

  // reduce across the 8 edge lanes (lanes differing in bits 3..5)
#pragma unroll
  for (int k = 0; k < 4; ++k) {
    int u = __builtin_bit_cast(int, acc[k]);
    acc[k] += H2((unsigned)__shfl_xor(u, 8));
    u = __builtin_bit_cast(int, acc[k]);
    acc[k] += H2((unsigned)__shfl_xor(u, 16));
    u = __builtin_bit_cast(int, acc[k]);
    acc[k] += H2((unsigned)__shfl_xor(u, 32));
  }

  if (g == 0 && nv) {                   // lanes 0..7: 8 x 16B = one full line
    float di = dinv[node];
    float f[8];
#pragma unroll
    for (int k = 0; k < 4; ++k) {
      f[2 * k] = (float)acc[k][0];
      f[2 * k + 1] = (float)acc[k][1];
    }
    const float* bb = b1 + t * 8;
    half2_t p[4];
#pragma unroll
    for (int k = 0; k < 4; ++k) {
      float e0 = fmaxf(fmaf(f[2 * k], di, bb[2 * k]), 0.f);
      float e1 = fmaxf(fmaf(f[2 * k + 1], di, bb[2 * k + 1]), 0.f);
      p[k] = half2_t{(_Float16)e0, (_Float16)e1};
    }
    uint4 wv;
    wv.x = __builtin_bit_cast(unsigned, p[0]);
    wv.y = __builtin_bit_cast(unsigned, p[1]);
    wv.z = __builtin_bit_cast(unsigned, p[2]);
    wv.w = __builtin_bit_cast(unsigned, p[3]);
    *(uint4*)(h1t + ((size_t)t * n + node) * 8) = wv;
  }
}

// ---------------- aggregation layer 2 (round-4 exact, unpadded 80B rows) -----
// 80B rows pack 1.6 rows/line -> 8MB unique footprint (padding to 128B rows
// measured WORSE in r8: +60% unique-line fill). Occupancy-protected.
template <int F, int S8, bool RELU, bool OUT_HALF>
__global__ __launch_bounds__(256) void k_agg_v4(const uint4* __restrict__ g8,
                                                const int* __restrict__ offset,
                                                const int* __restrict__ ssrc,
                                                const float* __restrict__ dinv,
                                                const float* __restrict__ bias,
                                                void* __restrict__ outp, int n) {
  constexpr int F8 = F / 8;
  int lane = threadIdx.x & 63;
  int g = lane >> 3;
  int t = lane & 7;
  int wave = (blockIdx.x * blockDim.x + threadIdx.x) >> 6;
  int nb = wave * 4;
  if (nb >= n) return;
  bool tv = t < F8;

  uint4 sv[4];
#pragma unroll
  for (int w = 0; w < 4; ++w) {
    int node = nb + w;
    int nc = node < n ? node : n - 1;
    sv[w] = (tv && g == 0 && node < n) ? g8[(size_t)nc * S8 + t]
                                       : make_uint4(0, 0, 0, 0);
  }

  int jj[4], ee[4];
  float di[4];
#pragma unroll
  for (int w = 0; w < 4; ++w) {
    int node = nb + w;
    bool nv = node < n;
    int nc = nv ? node : n - 1;
    int b0 = offset[nc];
    int b1 = offset[nc + 1];
    jj[w] = b0;
    ee[w] = nv ? b1 : b0;
    di[w] = dinv[nc];
  }

  half2_t acc[4][4];
#pragma unroll
  for (int w = 0; w < 4; ++w) {
#pragma unroll
    for (int k = 0; k < 4; ++k) acc[w][k] = H2(0u);
    addacc(acc[w], sv[w]);
  }

  for (;;) {
    bool a0[4], a1[4];
    bool any = false;
#pragma unroll
    for (int w = 0; w < 4; ++w) {
      a0[w] = jj[w] + 8 <= ee[w];
      a1[w] = jj[w] + 16 <= ee[w];
      any = any || a0[w];
    }
    if (!any) break;
    int s0[4], s1[4];
#pragma unroll
    for (int w = 0; w < 4; ++w) {
      s0[w] = a0[w] ? ssrc[jj[w] + g] : 0;
      s1[w] = a1[w] ? ssrc[jj[w] + 8 + g] : 0;
    }
    uint4 r0[4], r1[4];
#pragma unroll
    for (int w = 0; w < 4; ++w) {
      r0[w] = (a0[w] && tv) ? g8[(size_t)s0[w] * S8 + t] : make_uint4(0, 0, 0, 0);
      r1[w] = (a1[w] && tv) ? g8[(size_t)s1[w] * S8 + t] : make_uint4(0, 0, 0, 0);
    }
#pragma unroll
    for (int w = 0; w < 4; ++w) {
      addacc(acc[w], r0[w]);
      addacc(acc[w], r1[w]);
      jj[w] += a1[w] ? 16 : (a0[w] ? 8 : 0);
    }
  }

  {
    int rem[4];
    uint4 rv[4];
#pragma unroll
    for (int w = 0; w < 4; ++w) {
      rem[w] = ee[w] - jj[w];
      int gi = (g < rem[w]) ? g : (rem[w] - 1);
      int sW = rem[w] > 0 ? ssrc[jj[w] + gi] : 0;
      rv[w] = (tv && g < rem[w]) ? g8[(size_t)sW * S8 + t] : make_uint4(0, 0, 0, 0);
    }
#pragma unroll
    for (int w = 0; w < 4; ++w) addacc(acc[w], rv[w]);
  }

#pragma unroll
  for (int w = 0; w < 4; ++w) {
#pragma unroll
    for (int k = 0; k < 4; ++k) {
      int u = __builtin_bit_cast(int, acc[w][k]);
      acc[w][k] += H2((unsigned)__shfl_xor(u, 8));
      u = __builtin_bit_cast(int, acc[w][k]);
      acc[w][k] += H2((unsigned)__shfl_xor(u, 16));
      u = __builtin_bit_cast(int, acc[w][k]);
      acc[w][k] += H2((unsigned)__shfl_xor(u, 32));
    }
    int node = nb + w;
    if (node < n && lane < F8) {
      float f[8];
#pragma unroll
      for (int k = 0; k < 4; ++k) {
        f[2 * k] = (float)acc[w][k][0];
        f[2 * k + 1] = (float)acc[w][k][1];
      }
      const float* bb = bias + lane * 8;
      float o[8];
#pragma unroll
      for (int j = 0; j < 8; ++j) {
        o[j] = fmaf(f[j], di[w], bb[j]);
        if (RELU) o[j] = fmaxf(o[j], 0.f);
      }
      if (OUT_HALF) {
        _Float16* op = (_Float16*)outp + (size_t)node * F + lane * 8;
        half2_t p0 = {(_Float16)o[0], (_Float16)o[1]};
        half2_t p1 = {(_Float16)o[2], (_Float16)o[3]};
        half2_t p2 = {(_Float16)o[4], (_Float16)o[5]};
        half2_t p3 = {(_Float16)o[6], (_Float16)o[7]};
        uint4 wv;
        wv.x = __builtin_bit_cast(unsigned, p0);
        wv.y = __builtin_bit_cast(unsigned, p1);
        wv.z = __builtin_bit_cast(unsigned, p2);
        wv.w = __builtin_bit_cast(unsigned, p3);
        *(uint4*)op = wv;
      } else {
        float* op = (float*)outp + (size_t)node * F + lane * 8;
        *(float4*)op = make_float4(o[0], o[1], o[2], o[3]);
        *(float4*)(op + 4) = make_float4(o[4], o[5], o[6], o[7]);
      }
    }
  }
}

// ---------------- launch ----------------

extern "C" void kernel_launch(void* const* d_in, const int* in_sizes, int n_in,
                              void* d_out, int out_size, void* d_ws, size_t ws_size,
                              hipStream_t stream) {
  const float* x  = (const float*)d_in[0];
  const int*   ei = (const int*)d_in[1];
  const float* W1 = (const float*)d_in[2];
  const float* b1 = (const float*)d_in[3];
  const float* W2 = (const float*)d_in[4];
  const float* b2 = (const float*)d_in[5];
  float* out = (float*)d_out;

  const int F_IN = 128, HID = 64, C = 40;
  int N = in_sizes[0] / F_IN;
  int E = in_sizes[1] / 2;
  const int* src = ei;
  const int* dst = ei + E;
  int nbuck = (N + NPB - 1) >> NPB_SHIFT;   // 391 for N=100000

  char* w = (char*)d_ws;
  size_t o = 0;
  auto alloc = [&](size_t bytes) -> void* {
    void* p = w + o;
    o = (o + bytes + 255) & ~(size_t)255;
    return p;
  };
  float*    dinv   = (float*)alloc((size_t)N * 4);
  int*      offset = (int*)alloc((size_t)(N + 1) * 4);
  int*      bfill  = (int*)alloc(512 * 4);
  unsigned* tmp    = (unsigned*)alloc((size_t)nbuck * BCAP * 4);
  int*      ssrc   = (int*)alloc((size_t)E * 4);
  _Float16* g1t    = (_Float16*)alloc((size_t)N * HID * 2);   // slice-major [8][N]x16B
  _Float16* h1t    = (_Float16*)alloc((size_t)N * HID * 2);   // slice-major [8][N]x16B
  _Float16* g2     = (_Float16*)alloc((size_t)N * C * 2);     // node-major, stride 40

  dim3 b256(256);

  hipMemsetAsync(bfill, 0, 512 * 4, stream);
  k_partition<<<dim3((E + CHUNK - 1) / CHUNK), b256, 0, stream>>>(src, dst, bfill, tmp, E, nbuck);
  k_csr_build<<<dim3(nbuck), b256, 0, stream>>>(tmp, bfill, dinv, offset, ssrc, N, E, nbuck);

  // layer 1: g1T = dinv * (x @ W1) slice-major
  k_gemm_mfma<128, 64, 4, 4, 64, false, true, float><<<dim3(1536), b256, 0, stream>>>(
      x, W1, dinv, g1t, N);
  // sliced agg1: h1T = relu(dinv*(g1[self]+sum g1[src]) + b1), slice-major
  k_agg_slice<<<dim3(((N + 31) / 32) * 8), b256, 0, stream>>>(
      (const uint4*)g1t, offset, ssrc, dinv, b1, h1t, N);

  // layer 2: g2 = dinv * (h1 @ W2), node-major stride 40
  k_gemm_mfma<64, 40, 3, 2, 40, true, false, _Float16><<<dim3(1536), b256, 0, stream>>>(
      h1t, W2, dinv, g2, N);
  k_agg_v4<40, 5, false, false><<<dim3((N + 15) / 16), b256, 0, stream>>>(
      (const uint4*)g2, offset, ssrc, dinv, b2, out, N);
}

// Round 10
// 258.349 us; speedup vs baseline: 1.1636x; 1.0277x over previous
//
#include <hip/hip_runtime.h>
#include <hip/hip_fp16.h>
#include <cstdint>
#include <cstddef>

#define NPB_SHIFT 8                      // 256 dst-nodes per bucket
#define NPB (1 << NPB_SHIFT)
#define CHUNK 2048                       // edges per partition block (r8: occ 13.6%
                                         // grid-starved at 4096; 782 blocks now)
#define EPT (CHUNK / 256)                // edges per thread in partition
#define BCAP 6144                        // slots per bucket slab (lambda=4096, +32 sigma)
// nbuck = ceil(N/256) must be <= 512 (N <= 131072) for the LDS arrays below.

typedef _Float16 half8_t __attribute__((ext_vector_type(8)));
typedef _Float16 half4_t __attribute__((ext_vector_type(4)));
typedef _Float16 half2_t __attribute__((ext_vector_type(2)));
typedef float floatx4 __attribute__((ext_vector_type(4)));

#define H2(u) __builtin_bit_cast(half2_t, (u))

// ---------------- graph preprocessing (round-4 structure, proven) ------------
// Banned by measurement: scattered partial-line stores (r5, 3.2x), per-edge
// global atomic histograms (r8, +43us), agg1+gemm2 fusion (r7, occupancy),
// feature-sliced gathers (r9, transaction-bound).

__global__ __launch_bounds__(256) void k_partition(const int* __restrict__ src,
                                                   const int* __restrict__ dst,
                                                   int* __restrict__ bfill,
                                                   unsigned* __restrict__ tmp,
                                                   int E, int nbuck) {
  __shared__ int cnt[512];
  __shared__ int lbase[512];
  __shared__ int gdelta[512];
  __shared__ int cur[512];
  __shared__ int ps[256];
  __shared__ unsigned sval[CHUNK];
  __shared__ unsigned short sbid[CHUNK];
  int tid = threadIdx.x;
  int cbase = blockIdx.x * CHUNK;
  for (int i = tid; i < 512; i += 256) cnt[i] = 0;
  __syncthreads();
  int s[EPT], d[EPT];
  bool valid[EPT];
#pragma unroll
  for (int u = 0; u < EPT; ++u) {
    int e = cbase + u * 256 + tid;
    valid[u] = e < E;
    s[u] = valid[u] ? src[e] : 0;
    d[u] = valid[u] ? dst[e] : 0;
    if (valid[u]) atomicAdd(&cnt[d[u] >> NPB_SHIFT], 1);
  }
  __syncthreads();
  int c0 = cnt[2 * tid], c1 = cnt[2 * tid + 1];
  int p = c0 + c1;
  ps[tid] = p;
  __syncthreads();
  for (int off = 1; off < 256; off <<= 1) {
    int t = (tid >= off) ? ps[tid - off] : 0;
    __syncthreads();
    ps[tid] += t;
    __syncthreads();
  }
  int ep = ps[tid] - p;                  // exclusive over pairs
  lbase[2 * tid] = ep;
  lbase[2 * tid + 1] = ep + c0;
  __syncthreads();
  for (int i = tid; i < 512; i += 256) {
    cur[i] = lbase[i];
    if (cnt[i]) gdelta[i] = atomicAdd(&bfill[i], cnt[i]) - lbase[i];
  }
  __syncthreads();
#pragma unroll
  for (int u = 0; u < EPT; ++u) {
    if (valid[u]) {
      int b = d[u] >> NPB_SHIFT;
      int r = atomicAdd(&cur[b], 1);
      sval[r] = ((unsigned)s[u] << NPB_SHIFT) | (unsigned)(d[u] & (NPB - 1));
      sbid[r] = (unsigned short)b;
    }
  }
  __syncthreads();
  int nv = min(CHUNK, E - cbase);
  for (int i = tid; i < nv; i += 256) {
    unsigned v = sval[i];
    int b = sbid[i];
    tmp[(size_t)b * BCAP + (gdelta[b] + i)] = v;
  }
}

// per bucket: scan all bucket counts in-LDS -> dense base; LDS degree count ->
// dinv + dense offsets; then src-only CSR scatter into dense ssrc.
__global__ __launch_bounds__(256) void k_csr_build(const unsigned* __restrict__ tmp,
                                                   const int* __restrict__ bfill,
                                                   float* __restrict__ dinv,
                                                   int* __restrict__ offset,
                                                   int* __restrict__ ssrc,
                                                   int N, int E, int nbuck) {
  __shared__ int cnt[NPB];
  __shared__ int scan[NPB];
  __shared__ int fillL[NPB];
  __shared__ int bs[512];
  __shared__ int ps[256];
  int b = blockIdx.x, tid = threadIdx.x;
  int nbase = b << NPB_SHIFT;
  int nloc = min(NPB, N - nbase);
  cnt[tid] = 0;
  bs[tid] = (tid < nbuck) ? bfill[tid] : 0;
  bs[tid + 256] = (tid + 256 < nbuck) ? bfill[tid + 256] : 0;
  __syncthreads();
  int c0 = bs[2 * tid], c1 = bs[2 * tid + 1];
  int pp = c0 + c1;
  ps[tid] = pp;
  __syncthreads();
  for (int off = 1; off < 256; off <<= 1) {
    int t = (tid >= off) ? ps[tid - off] : 0;
    __syncthreads();
    ps[tid] += t;
    __syncthreads();
  }
  int ep = ps[tid] - pp;
  bs[2 * tid] = ep;
  bs[2 * tid + 1] = ep + c0;
  __syncthreads();
  int ebeg = bs[b];                    // dense base of this bucket
  int cntB = bfill[b];
  int sbeg = b * BCAP;
  int send = sbeg + cntB;
  for (int j = sbeg + tid; j < send; j += 256) atomicAdd(&cnt[tmp[j] & (NPB - 1)], 1);
  __syncthreads();
  int v = cnt[tid];
  scan[tid] = v;
  __syncthreads();
  for (int off = 1; off < NPB; off <<= 1) {
    int t = (tid >= off) ? scan[tid - off] : 0;
    __syncthreads();
    scan[tid] += t;
    __syncthreads();
  }
  int myoff = ebeg + scan[tid] - v;
  fillL[tid] = myoff;
  if (tid < nloc) {
    offset[nbase + tid] = myoff;
    dinv[nbase + tid] = rsqrtf((float)(v + 1));   // +1 self-loop
  }
  if (b == nbuck - 1 && tid == NPB - 1) offset[N] = ebeg + scan[tid];   // == E
  __syncthreads();
  int j = sbeg + tid;
  for (; j + 3 * 256 < send; j += 4 * 256) {
    unsigned p[4];
#pragma unroll
    for (int u = 0; u < 4; ++u) p[u] = tmp[j + u * 256];
#pragma unroll
    for (int u = 0; u < 4; ++u) {
      int pos = atomicAdd(&fillL[p[u] & (NPB - 1)], 1);
      ssrc[pos] = (int)(p[u] >> NPB_SHIFT);
    }
  }
  for (; j < send; j += 256) {
    unsigned p = tmp[j];
    int pos = atomicAdd(&fillL[p & (NPB - 1)], 1);
    ssrc[pos] = (int)(p >> NPB_SHIFT);
  }
}

// ---------------- dense layers: MFMA 16x16x32 f16, output scaled by dinv ------
// Writes g[node] = dinv[node] * (x @ W)[node] as fp16, row stride OS.
template <int K, int COLS, int MT, int KC, int OS, typename XT>
__global__ __launch_bounds__(256) void k_gemm_mfma(const XT* __restrict__ x,
                                                   const float* __restrict__ W,
                                                   const float* __restrict__ dinv,
                                                   _Float16* __restrict__ out, int n) {
  int lane = threadIdx.x & 63;
  int quad = lane >> 4;
  int l15 = lane & 15;
  int gwave = (blockIdx.x * blockDim.x + threadIdx.x) >> 6;
  int nwave = (gridDim.x * blockDim.x) >> 6;
  int ntiles = (n + 15) >> 4;

  half8_t afrag[MT][KC];
#pragma unroll
  for (int m = 0; m < MT; ++m) {
    int colw = m * 16 + l15;
    if (colw > COLS - 1) colw = COLS - 1;
#pragma unroll
    for (int c = 0; c < KC; ++c) {
#pragma unroll
      for (int j = 0; j < 8; ++j) {
        int kk = c * 32 + quad * 8 + j;
        afrag[m][c][j] = (_Float16)W[kk * COLS + colw];
      }
    }
  }

  for (int tile = gwave; tile < ntiles; tile += nwave) {
    int node0 = tile << 4;
    int nodeB = node0 + l15;
    int nodeC = nodeB < n ? nodeB : n - 1;
    const XT* xr = x + (size_t)nodeC * K;
    float dv = dinv[nodeC];
    half8_t bfrag[KC];
#pragma unroll
    for (int c = 0; c < KC; ++c) {
      if constexpr (sizeof(XT) == 4) {
        float4 lo = *(const float4*)(xr + c * 32 + quad * 8);
        float4 hi = *(const float4*)(xr + c * 32 + quad * 8 + 4);
        bfrag[c][0] = (_Float16)lo.x; bfrag[c][1] = (_Float16)lo.y;
        bfrag[c][2] = (_Float16)lo.z; bfrag[c][3] = (_Float16)lo.w;
        bfrag[c][4] = (_Float16)hi.x; bfrag[c][5] = (_Float16)hi.y;
        bfrag[c][6] = (_Float16)hi.z; bfrag[c][7] = (_Float16)hi.w;
      } else {
        bfrag[c] = *(const half8_t*)(xr + c * 32 + quad * 8);
      }
    }
    floatx4 acc[MT];
#pragma unroll
    for (int m = 0; m < MT; ++m) acc[m] = (floatx4){0.f, 0.f, 0.f, 0.f};
#pragma unroll
    for (int c = 0; c < KC; ++c)
#pragma unroll
      for (int m = 0; m < MT; ++m)
        acc[m] = __builtin_amdgcn_mfma_f32_16x16x32_f16(afrag[m][c], bfrag[c], acc[m], 0, 0, 0);

    if (nodeB < n) {
#pragma unroll
      for (int m = 0; m < MT; ++m) {
        int colBase = m * 16 + quad * 4;
        if (colBase < COLS) {
          half4_t hv = {(_Float16)(acc[m][0] * dv), (_Float16)(acc[m][1] * dv),
                        (_Float16)(acc[m][2] * dv), (_Float16)(acc[m][3] * dv)};
          *(half4_t*)(out + (size_t)nodeB * OS + colBase) = hv;
        }
      }
    }
  }
}

// ---------------- aggregation: 4 nodes per wave, 8 gathers in flight ----------
// Fill-limited at the random-128B-line wall (~2.26 TB/s, 91MB = 12.8MB x 8
// XCDs). Measured: more MLP = 0 (r2); less occupancy = much worse (r7);
// feature-slicing = transaction-bound, worse (r9). Do not restructure.

__device__ __forceinline__ void addacc(half2_t* acc, uint4 r) {
  acc[0] += H2(r.x); acc[1] += H2(r.y); acc[2] += H2(r.z); acc[3] += H2(r.w);
}

template <int F, int S8, bool RELU, bool OUT_HALF>
__global__ __launch_bounds__(256) void k_agg_v4(const uint4* __restrict__ g8,
                                                const int* __restrict__ offset,
                                                const int* __restrict__ ssrc,
                                                const float* __restrict__ dinv,
                                                const float* __restrict__ bias,
                                                void* __restrict__ outp, int n) {
  constexpr int F8 = F / 8;            // used octets per row (8 or 5)
  int lane = threadIdx.x & 63;
  int g = lane >> 3;                   // edge group 0..7
  int t = lane & 7;                    // feature octet
  int wave = (blockIdx.x * blockDim.x + threadIdx.x) >> 6;
  int nb = wave * 4;                   // first node of this wave
  if (nb >= n) return;
  bool tv = t < F8;

  uint4 sv[4];
#pragma unroll
  for (int w = 0; w < 4; ++w) {
    int node = nb + w;
    int nc = node < n ? node : n - 1;
    sv[w] = (tv && g == 0 && node < n) ? g8[(size_t)nc * S8 + t]
                                       : make_uint4(0, 0, 0, 0);
  }

  int jj[4], ee[4];
  float di[4];
#pragma unroll
  for (int w = 0; w < 4; ++w) {
    int node = nb + w;
    bool nv = node < n;
    int nc = nv ? node : n - 1;
    int b0 = offset[nc];
    int b1 = offset[nc + 1];
    jj[w] = b0;
    ee[w] = nv ? b1 : b0;
    di[w] = dinv[nc];
  }

  half2_t acc[4][4];
#pragma unroll
  for (int w = 0; w < 4; ++w) {
#pragma unroll
    for (int k = 0; k < 4; ++k) acc[w][k] = H2(0u);
    addacc(acc[w], sv[w]);
  }

  for (;;) {
    bool a0[4], a1[4];
    bool any = false;
#pragma unroll
    for (int w = 0; w < 4; ++w) {
      a0[w] = jj[w] + 8 <= ee[w];
      a1[w] = jj[w] + 16 <= ee[w];
      any = any || a0[w];
    }
    if (!any) break;
    int s0[4], s1[4];
#pragma unroll
    for (int w = 0; w < 4; ++w) {
      s0[w] = a0[w] ? ssrc[jj[w] + g] : 0;
      s1[w] = a1[w] ? ssrc[jj[w] + 8 + g] : 0;
    }
    uint4 r0[4], r1[4];
#pragma unroll
    for (int w = 0; w < 4; ++w) {
      r0[w] = (a0[w] && tv) ? g8[(size_t)s0[w] * S8 + t] : make_uint4(0, 0, 0, 0);
      r1[w] = (a1[w] && tv) ? g8[(size_t)s1[w] * S8 + t] : make_uint4(0, 0, 0, 0);
    }
#pragma unroll
    for (int w = 0; w < 4; ++w) {
      addacc(acc[w], r0[w]);
      addacc(acc[w], r1[w]);
      jj[w] += a1[w] ? 16 : (a0[w] ? 8 : 0);
    }
  }

  {
    int rem[4];
    uint4 rv[4];
#pragma unroll
    for (int w = 0; w < 4; ++w) {
      rem[w] = ee[w] - jj[w];
      int gi = (g < rem[w]) ? g : (rem[w] - 1);
      int sW = rem[w] > 0 ? ssrc[jj[w] + gi] : 0;
      rv[w] = (tv && g < rem[w]) ? g8[(size_t)sW * S8 + t] : make_uint4(0, 0, 0, 0);
    }
#pragma unroll
    for (int w = 0; w < 4; ++w) addacc(acc[w], rv[w]);
  }

#pragma unroll
  for (int w = 0; w < 4; ++w) {
#pragma unroll
    for (int k = 0; k < 4; ++k) {
      int u = __builtin_bit_cast(int, acc[w][k]);
      acc[w][k] += H2((unsigned)__shfl_xor(u, 8));
      u = __builtin_bit_cast(int, acc[w][k]);
      acc[w][k] += H2((unsigned)__shfl_xor(u, 16));
      u = __builtin_bit_cast(int, acc[w][k]);
      acc[w][k] += H2((unsigned)__shfl_xor(u, 32));
    }
    int node = nb + w;
    if (node < n && lane < F8) {
      float f[8];
#pragma unroll
      for (int k = 0; k < 4; ++k) {
        f[2 * k] = (float)acc[w][k][0];
        f[2 * k + 1] = (float)acc[w][k][1];
      }
      const float* bb = bias + lane * 8;
      float o[8];
#pragma unroll
      for (int j = 0; j < 8; ++j) {
        o[j] = fmaf(f[j], di[w], bb[j]);
        if (RELU) o[j] = fmaxf(o[j], 0.f);
      }
      if (OUT_HALF) {
        _Float16* op = (_Float16*)outp + (size_t)node * F + lane * 8;
        half2_t p0 = {(_Float16)o[0], (_Float16)o[1]};
        half2_t p1 = {(_Float16)o[2], (_Float16)o[3]};
        half2_t p2 = {(_Float16)o[4], (_Float16)o[5]};
        half2_t p3 = {(_Float16)o[6], (_Float16)o[7]};
        uint4 wv;
        wv.x = __builtin_bit_cast(unsigned, p0);
        wv.y = __builtin_bit_cast(unsigned, p1);
        wv.z = __builtin_bit_cast(unsigned, p2);
        wv.w = __builtin_bit_cast(unsigned, p3);
        *(uint4*)op = wv;
      } else {
        float* op = (float*)outp + (size_t)node * F + lane * 8;
        *(float4*)op = make_float4(o[0], o[1], o[2], o[3]);
        *(float4*)(op + 4) = make_float4(o[4], o[5], o[6], o[7]);
      }
    }
  }
}

// ---------------- launch ----------------

extern "C" void kernel_launch(void* const* d_in, const int* in_sizes, int n_in,
                              void* d_out, int out_size, void* d_ws, size_t ws_size,
                              hipStream_t stream) {
  const float* x  = (const float*)d_in[0];
  const int*   ei = (const int*)d_in[1];
  const float* W1 = (const float*)d_in[2];
  const float* b1 = (const float*)d_in[3];
  const float* W2 = (const float*)d_in[4];
  const float* b2 = (const float*)d_in[5];
  float* out = (float*)d_out;

  const int F_IN = 128, HID = 64, C = 40;
  int N = in_sizes[0] / F_IN;
  int E = in_sizes[1] / 2;
  const int* src = ei;
  const int* dst = ei + E;
  int nbuck = (N + NPB - 1) >> NPB_SHIFT;   // 391 for N=100000

  char* w = (char*)d_ws;
  size_t o = 0;
  auto alloc = [&](size_t bytes) -> void* {
    void* p = w + o;
    o = (o + bytes + 255) & ~(size_t)255;
    return p;
  };
  float*    dinv   = (float*)alloc((size_t)N * 4);
  int*      offset = (int*)alloc((size_t)(N + 1) * 4);
  int*      bfill  = (int*)alloc(512 * 4);
  unsigned* tmp    = (unsigned*)alloc((size_t)nbuck * BCAP * 4);
  int*      ssrc   = (int*)alloc((size_t)E * 4);
  _Float16* g1     = (_Float16*)alloc((size_t)N * HID * 2);   // dinv*(xW1), stride 64
  _Float16* h1     = (_Float16*)alloc((size_t)N * HID * 2);   // relu layer-1 out, fp16
  _Float16* g2     = (_Float16*)alloc((size_t)N * C * 2);     // dinv*(h1W2), stride 40

  dim3 b256(256);

  // partition into per-bucket slabs + dense CSR compaction
  hipMemsetAsync(bfill, 0, 512 * 4, stream);
  k_partition<<<dim3((E + CHUNK - 1) / CHUNK), b256, 0, stream>>>(src, dst, bfill, tmp, E, nbuck);
  k_csr_build<<<dim3(nbuck), b256, 0, stream>>>(tmp, bfill, dinv, offset, ssrc, N, E, nbuck);

  // layer 1: g1 = dinv * (x @ W1);  h1 = relu(dinv*(g1[self]+sum g1[src]) + b1)
  k_gemm_mfma<128, 64, 4, 4, 64, float><<<dim3(1536), b256, 0, stream>>>(x, W1, dinv, g1, N);
  k_agg_v4<64, 8, true, true><<<dim3((N + 15) / 16), b256, 0, stream>>>(
      (const uint4*)g1, offset, ssrc, dinv, b1, h1, N);

  // layer 2: g2 = dinv * (h1 @ W2); out = dinv*(g2[self]+sum g2[src]) + b2
  k_gemm_mfma<64, 40, 3, 2, 40, _Float16><<<dim3(1536), b256, 0, stream>>>(h1, W2, dinv, g2, N);
  k_agg_v4<40, 5, false, false><<<dim3((N + 15) / 16), b256, 0, stream>>>(
      (const uint4*)g2, offset, ssrc, dinv, b2, out, N);
}

// Round 11
// 253.687 us; speedup vs baseline: 1.1849x; 1.0184x over previous
//
#include <hip/hip_runtime.h>
#include <hip/hip_fp16.h>
#include <cstdint>
#include <cstddef>

#define NPB_SHIFT 9                      // 512 dst-nodes per bucket (r11: longer
#define NPB (1 << NPB_SHIFT)             // tmp write runs: 21 edges/84B vs 10/40B)
#define CHUNK 4096                       // edges per partition block (r10's 2048: +7us,
#define EPT (CHUNK / 256)                // write runs halved -- runs dominate occupancy)
#define BCAP 9728                        // slots per bucket slab (lambda=8192, +17 sigma)
// nbuck = ceil(N/512) must be <= 512 (N <= 262144) for the LDS arrays below.

typedef _Float16 half8_t __attribute__((ext_vector_type(8)));
typedef _Float16 half4_t __attribute__((ext_vector_type(4)));
typedef _Float16 half2_t __attribute__((ext_vector_type(2)));
typedef float floatx4 __attribute__((ext_vector_type(4)));

#define H2(u) __builtin_bit_cast(half2_t, (u))

// ---------------- graph preprocessing (round-4 structure, proven) ------------
// Banned by measurement: scattered partial-line stores (r5, 3.2x), per-edge
// global atomic histograms (r8, +43us), agg1+gemm2 fusion (r7, occupancy),
// feature-sliced gathers (r9, transaction-bound), short write runs (r10, +7us).

__global__ __launch_bounds__(256) void k_partition(const int* __restrict__ src,
                                                   const int* __restrict__ dst,
                                                   int* __restrict__ bfill,
                                                   unsigned* __restrict__ tmp,
                                                   int E, int nbuck) {
  __shared__ int cnt[512];
  __shared__ int lbase[512];
  __shared__ int gdelta[512];
  __shared__ int cur[512];
  __shared__ int ps[256];
  __shared__ unsigned sval[CHUNK];
  __shared__ unsigned short sbid[CHUNK];
  int tid = threadIdx.x;
  int cbase = blockIdx.x * CHUNK;
  for (int i = tid; i < 512; i += 256) cnt[i] = 0;
  __syncthreads();
  int s[EPT], d[EPT];
  bool valid[EPT];
#pragma unroll
  for (int u = 0; u < EPT; ++u) {
    int e = cbase + u * 256 + tid;
    valid[u] = e < E;
    s[u] = valid[u] ? src[e] : 0;
    d[u] = valid[u] ? dst[e] : 0;
    if (valid[u]) atomicAdd(&cnt[d[u] >> NPB_SHIFT], 1);
  }
  __syncthreads();
  int c0 = cnt[2 * tid], c1 = cnt[2 * tid + 1];
  int p = c0 + c1;
  ps[tid] = p;
  __syncthreads();
  for (int off = 1; off < 256; off <<= 1) {
    int t = (tid >= off) ? ps[tid - off] : 0;
    __syncthreads();
    ps[tid] += t;
    __syncthreads();
  }
  int ep = ps[tid] - p;                  // exclusive over pairs
  lbase[2 * tid] = ep;
  lbase[2 * tid + 1] = ep + c0;
  __syncthreads();
  for (int i = tid; i < 512; i += 256) {
    cur[i] = lbase[i];
    if (cnt[i]) gdelta[i] = atomicAdd(&bfill[i], cnt[i]) - lbase[i];
  }
  __syncthreads();
#pragma unroll
  for (int u = 0; u < EPT; ++u) {
    if (valid[u]) {
      int b = d[u] >> NPB_SHIFT;
      int r = atomicAdd(&cur[b], 1);
      sval[r] = ((unsigned)s[u] << NPB_SHIFT) | (unsigned)(d[u] & (NPB - 1));
      sbid[r] = (unsigned short)b;
    }
  }
  __syncthreads();
  int nv = min(CHUNK, E - cbase);
  for (int i = tid; i < nv; i += 256) {
    unsigned v = sval[i];
    int b = sbid[i];
    tmp[(size_t)b * BCAP + (gdelta[b] + i)] = v;
  }
}

// per bucket: scan all bucket counts in-LDS -> dense base; LDS degree count
// over 512 nodes (pair-scan, 256 threads) -> dinv + dense offsets; then
// src-only CSR scatter into dense ssrc.
__global__ __launch_bounds__(256) void k_csr_build(const unsigned* __restrict__ tmp,
                                                   const int* __restrict__ bfill,
                                                   float* __restrict__ dinv,
                                                   int* __restrict__ offset,
                                                   int* __restrict__ ssrc,
                                                   int N, int E, int nbuck) {
  __shared__ int cnt[NPB];
  __shared__ int fillL[NPB];
  __shared__ int bs[512];
  __shared__ int ps[256];
  __shared__ int ps2[256];
  int b = blockIdx.x, tid = threadIdx.x;
  int nbase = b << NPB_SHIFT;
  int nloc = min(NPB, N - nbase);
  cnt[tid] = 0;
  cnt[tid + 256] = 0;
  bs[tid] = (tid < nbuck) ? bfill[tid] : 0;
  bs[tid + 256] = (tid + 256 < nbuck) ? bfill[tid + 256] : 0;
  __syncthreads();
  // pair-scan of bucket counts -> dense bucket bases
  int c0 = bs[2 * tid], c1 = bs[2 * tid + 1];
  int pp = c0 + c1;
  ps[tid] = pp;
  __syncthreads();
  for (int off = 1; off < 256; off <<= 1) {
    int t = (tid >= off) ? ps[tid - off] : 0;
    __syncthreads();
    ps[tid] += t;
    __syncthreads();
  }
  int ep = ps[tid] - pp;
  bs[2 * tid] = ep;
  bs[2 * tid + 1] = ep + c0;
  __syncthreads();
  int ebeg = bs[b];                    // dense base of this bucket
  int cntB = bfill[b];
  int sbeg = b * BCAP;
  int send = sbeg + cntB;
  // per-node degree count within bucket
  for (int j = sbeg + tid; j < send; j += 256) atomicAdd(&cnt[tmp[j] & (NPB - 1)], 1);
  __syncthreads();
  // pair-scan of 512 node degrees with 256 threads
  int d0 = cnt[2 * tid], d1 = cnt[2 * tid + 1];
  int dp = d0 + d1;
  ps2[tid] = dp;
  __syncthreads();
  for (int off = 1; off < 256; off <<= 1) {
    int t = (tid >= off) ? ps2[tid - off] : 0;
    __syncthreads();
    ps2[tid] += t;
    __syncthreads();
  }
  int ep2 = ps2[tid] - dp;             // exclusive over node pairs
  int off0 = ebeg + ep2;               // node 2*tid
  int off1 = ebeg + ep2 + d0;          // node 2*tid+1
  fillL[2 * tid] = off0;
  fillL[2 * tid + 1] = off1;
  if (2 * tid < nloc) {
    offset[nbase + 2 * tid] = off0;
    dinv[nbase + 2 * tid] = rsqrtf((float)(d0 + 1));   // +1 self-loop
  }
  if (2 * tid + 1 < nloc) {
    offset[nbase + 2 * tid + 1] = off1;
    dinv[nbase + 2 * tid + 1] = rsqrtf((float)(d1 + 1));
  }
  if (b == nbuck - 1 && tid == 0) offset[N] = ebeg + cntB;   // == E
  __syncthreads();
  // scatter src indices into exact dense CSR slots
  int j = sbeg + tid;
  for (; j + 3 * 256 < send; j += 4 * 256) {
    unsigned p[4];
#pragma unroll
    for (int u = 0; u < 4; ++u) p[u] = tmp[j + u * 256];
#pragma unroll
    for (int u = 0; u < 4; ++u) {
      int pos = atomicAdd(&fillL[p[u] & (NPB - 1)], 1);
      ssrc[pos] = (int)(p[u] >> NPB_SHIFT);
    }
  }
  for (; j < send; j += 256) {
    unsigned p = tmp[j];
    int pos = atomicAdd(&fillL[p & (NPB - 1)], 1);
    ssrc[pos] = (int)(p >> NPB_SHIFT);
  }
}

// ---------------- dense layers: MFMA 16x16x32 f16, output scaled by dinv ------
// Writes g[node] = dinv[node] * (x @ W)[node] as fp16, row stride OS.
template <int K, int COLS, int MT, int KC, int OS, typename XT>
__global__ __launch_bounds__(256) void k_gemm_mfma(const XT* __restrict__ x,
                                                   const float* __restrict__ W,
                                                   const float* __restrict__ dinv,
                                                   _Float16* __restrict__ out, int n) {
  int lane = threadIdx.x & 63;
  int quad = lane >> 4;
  int l15 = lane & 15;
  int gwave = (blockIdx.x * blockDim.x + threadIdx.x) >> 6;
  int nwave = (gridDim.x * blockDim.x) >> 6;
  int ntiles = (n + 15) >> 4;

  half8_t afrag[MT][KC];
#pragma unroll
  for (int m = 0; m < MT; ++m) {
    int colw = m * 16 + l15;
    if (colw > COLS - 1) colw = COLS - 1;
#pragma unroll
    for (int c = 0; c < KC; ++c) {
#pragma unroll
      for (int j = 0; j < 8; ++j) {
        int kk = c * 32 + quad * 8 + j;
        afrag[m][c][j] = (_Float16)W[kk * COLS + colw];
      }
    }
  }

  for (int tile = gwave; tile < ntiles; tile += nwave) {
    int node0 = tile << 4;
    int nodeB = node0 + l15;
    int nodeC = nodeB < n ? nodeB : n - 1;
    const XT* xr = x + (size_t)nodeC * K;
    float dv = dinv[nodeC];
    half8_t bfrag[KC];
#pragma unroll
    for (int c = 0; c < KC; ++c) {
      if constexpr (sizeof(XT) == 4) {
        float4 lo = *(const float4*)(xr + c * 32 + quad * 8);
        float4 hi = *(const float4*)(xr + c * 32 + quad * 8 + 4);
        bfrag[c][0] = (_Float16)lo.x; bfrag[c][1] = (_Float16)lo.y;
        bfrag[c][2] = (_Float16)lo.z; bfrag[c][3] = (_Float16)lo.w;
        bfrag[c][4] = (_Float16)hi.x; bfrag[c][5] = (_Float16)hi.y;
        bfrag[c][6] = (_Float16)hi.z; bfrag[c][7] = (_Float16)hi.w;
      } else {
        bfrag[c] = *(const half8_t*)(xr + c * 32 + quad * 8);
      }
    }
    floatx4 acc[MT];
#pragma unroll
    for (int m = 0; m < MT; ++m) acc[m] = (floatx4){0.f, 0.f, 0.f, 0.f};
#pragma unroll
    for (int c = 0; c < KC; ++c)
#pragma unroll
      for (int m = 0; m < MT; ++m)
        acc[m] = __builtin_amdgcn_mfma_f32_16x16x32_f16(afrag[m][c], bfrag[c], acc[m], 0, 0, 0);

    if (nodeB < n) {
#pragma unroll
      for (int m = 0; m < MT; ++m) {
        int colBase = m * 16 + quad * 4;
        if (colBase < COLS) {
          half4_t hv = {(_Float16)(acc[m][0] * dv), (_Float16)(acc[m][1] * dv),
                        (_Float16)(acc[m][2] * dv), (_Float16)(acc[m][3] * dv)};
          *(half4_t*)(out + (size_t)nodeB * OS + colBase) = hv;
        }
      }
    }
  }
}

// ---------------- aggregation: 4 nodes per wave, 8 gathers in flight ----------
// Fill-limited at the random-128B-line wall (~2.26 TB/s, 91MB = 12.8MB x
// 8 XCDs x (1-e^-2)). Measured: more MLP = 0 (r2); less occupancy = much
// worse (r7); feature-slicing = transaction-bound, worse (r9). Do not
// restructure.

__device__ __forceinline__ void addacc(half2_t* acc, uint4 r) {
  acc[0] += H2(r.x); acc[1] += H2(r.y); acc[2] += H2(r.z); acc[3] += H2(r.w);
}

template <int F, int S8, bool RELU, bool OUT_HALF>
__global__ __launch_bounds__(256) void k_agg_v4(const uint4* __restrict__ g8,
                                                const int* __restrict__ offset,
                                                const int* __restrict__ ssrc,
                                                const float* __restrict__ dinv,
                                                const float* __restrict__ bias,
                                                void* __restrict__ outp, int n) {
  constexpr int F8 = F / 8;            // used octets per row (8 or 5)
  int lane = threadIdx.x & 63;
  int g = lane >> 3;                   // edge group 0..7
  int t = lane & 7;                    // feature octet
  int wave = (blockIdx.x * blockDim.x + threadIdx.x) >> 6;
  int nb = wave * 4;                   // first node of this wave
  if (nb >= n) return;
  bool tv = t < F8;

  uint4 sv[4];
#pragma unroll
  for (int w = 0; w < 4; ++w) {
    int node = nb + w;
    int nc = node < n ? node : n - 1;
    sv[w] = (tv && g == 0 && node < n) ? g8[(size_t)nc * S8 + t]
                                       : make_uint4(0, 0, 0, 0);
  }

  int jj[4], ee[4];
  float di[4];
#pragma unroll
  for (int w = 0; w < 4; ++w) {
    int node = nb + w;
    bool nv = node < n;
    int nc = nv ? node : n - 1;
    int b0 = offset[nc];
    int b1 = offset[nc + 1];
    jj[w] = b0;
    ee[w] = nv ? b1 : b0;
    di[w] = dinv[nc];
  }

  half2_t acc[4][4];
#pragma unroll
  for (int w = 0; w < 4; ++w) {
#pragma unroll
    for (int k = 0; k < 4; ++k) acc[w][k] = H2(0u);
    addacc(acc[w], sv[w]);
  }

  for (;;) {
    bool a0[4], a1[4];
    bool any = false;
#pragma unroll
    for (int w = 0; w < 4; ++w) {
      a0[w] = jj[w] + 8 <= ee[w];
      a1[w] = jj[w] + 16 <= ee[w];
      any = any || a0[w];
    }
    if (!any) break;
    int s0[4], s1[4];
#pragma unroll
    for (int w = 0; w < 4; ++w) {
      s0[w] = a0[w] ? ssrc[jj[w] + g] : 0;
      s1[w] = a1[w] ? ssrc[jj[w] + 8 + g] : 0;
    }
    uint4 r0[4], r1[4];
#pragma unroll
    for (int w = 0; w < 4; ++w) {
      r0[w] = (a0[w] && tv) ? g8[(size_t)s0[w] * S8 + t] : make_uint4(0, 0, 0, 0);
      r1[w] = (a1[w] && tv) ? g8[(size_t)s1[w] * S8 + t] : make_uint4(0, 0, 0, 0);
    }
#pragma unroll
    for (int w = 0; w < 4; ++w) {
      addacc(acc[w], r0[w]);
      addacc(acc[w], r1[w]);
      jj[w] += a1[w] ? 16 : (a0[w] ? 8 : 0);
    }
  }

  {
    int rem[4];
    uint4 rv[4];
#pragma unroll
    for (int w = 0; w < 4; ++w) {
      rem[w] = ee[w] - jj[w];
      int gi = (g < rem[w]) ? g : (rem[w] - 1);
      int sW = rem[w] > 0 ? ssrc[jj[w] + gi] : 0;
      rv[w] = (tv && g < rem[w]) ? g8[(size_t)sW * S8 + t] : make_uint4(0, 0, 0, 0);
    }
#pragma unroll
    for (int w = 0; w < 4; ++w) addacc(acc[w], rv[w]);
  }

#pragma unroll
  for (int w = 0; w < 4; ++w) {
#pragma unroll
    for (int k = 0; k < 4; ++k) {
      int u = __builtin_bit_cast(int, acc[w][k]);
      acc[w][k] += H2((unsigned)__shfl_xor(u, 8));
      u = __builtin_bit_cast(int, acc[w][k]);
      acc[w][k] += H2((unsigned)__shfl_xor(u, 16));
      u = __builtin_bit_cast(int, acc[w][k]);
      acc[w][k] += H2((unsigned)__shfl_xor(u, 32));
    }
    int node = nb + w;
    if (node < n && lane < F8) {
      float f[8];
#pragma unroll
      for (int k = 0; k < 4; ++k) {
        f[2 * k] = (float)acc[w][k][0];
        f[2 * k + 1] = (float)acc[w][k][1];
      }
      const float* bb = bias + lane * 8;
      float o[8];
#pragma unroll
      for (int j = 0; j < 8; ++j) {
        o[j] = fmaf(f[j], di[w], bb[j]);
        if (RELU) o[j] = fmaxf(o[j], 0.f);
      }
      if (OUT_HALF) {
        _Float16* op = (_Float16*)outp + (size_t)node * F + lane * 8;
        half2_t p0 = {(_Float16)o[0], (_Float16)o[1]};
        half2_t p1 = {(_Float16)o[2], (_Float16)o[3]};
        half2_t p2 = {(_Float16)o[4], (_Float16)o[5]};
        half2_t p3 = {(_Float16)o[6], (_Float16)o[7]};
        uint4 wv;
        wv.x = __builtin_bit_cast(unsigned, p0);
        wv.y = __builtin_bit_cast(unsigned, p1);
        wv.z = __builtin_bit_cast(unsigned, p2);
        wv.w = __builtin_bit_cast(unsigned, p3);
        *(uint4*)op = wv;
      } else {
        float* op = (float*)outp + (size_t)node * F + lane * 8;
        *(float4*)op = make_float4(o[0], o[1], o[2], o[3]);
        *(float4*)(op + 4) = make_float4(o[4], o[5], o[6], o[7]);
      }
    }
  }
}

// ---------------- launch ----------------

extern "C" void kernel_launch(void* const* d_in, const int* in_sizes, int n_in,
                              void* d_out, int out_size, void* d_ws, size_t ws_size,
                              hipStream_t stream) {
  const float* x  = (const float*)d_in[0];
  const int*   ei = (const int*)d_in[1];
  const float* W1 = (const float*)d_in[2];
  const float* b1 = (const float*)d_in[3];
  const float* W2 = (const float*)d_in[4];
  const float* b2 = (const float*)d_in[5];
  float* out = (float*)d_out;

  const int F_IN = 128, HID = 64, C = 40;
  int N = in_sizes[0] / F_IN;
  int E = in_sizes[1] / 2;
  const int* src = ei;
  const int* dst = ei + E;
  int nbuck = (N + NPB - 1) >> NPB_SHIFT;   // 196 for N=100000

  char* w = (char*)d_ws;
  size_t o = 0;
  auto alloc = [&](size_t bytes) -> void* {
    void* p = w + o;
    o = (o + bytes + 255) & ~(size_t)255;
    return p;
  };
  float*    dinv   = (float*)alloc((size_t)N * 4);
  int*      offset = (int*)alloc((size_t)(N + 1) * 4);
  int*      bfill  = (int*)alloc(512 * 4);
  unsigned* tmp    = (unsigned*)alloc((size_t)nbuck * BCAP * 4);
  int*      ssrc   = (int*)alloc((size_t)E * 4);
  _Float16* g1     = (_Float16*)alloc((size_t)N * HID * 2);   // dinv*(xW1), stride 64
  _Float16* h1     = (_Float16*)alloc((size_t)N * HID * 2);   // relu layer-1 out, fp16
  _Float16* g2     = (_Float16*)alloc((size_t)N * C * 2);     // dinv*(h1W2), stride 40

  dim3 b256(256);

  // partition into per-bucket slabs + dense CSR compaction
  hipMemsetAsync(bfill, 0, 512 * 4, stream);
  k_partition<<<dim3((E + CHUNK - 1) / CHUNK), b256, 0, stream>>>(src, dst, bfill, tmp, E, nbuck);
  k_csr_build<<<dim3(nbuck), b256, 0, stream>>>(tmp, bfill, dinv, offset, ssrc, N, E, nbuck);

  // layer 1: g1 = dinv * (x @ W1);  h1 = relu(dinv*(g1[self]+sum g1[src]) + b1)
  k_gemm_mfma<128, 64, 4, 4, 64, float><<<dim3(1536), b256, 0, stream>>>(x, W1, dinv, g1, N);
  k_agg_v4<64, 8, true, true><<<dim3((N + 15) / 16), b256, 0, stream>>>(
      (const uint4*)g1, offset, ssrc, dinv, b1, h1, N);

  // layer 2: g2 = dinv * (h1 @ W2); out = dinv*(g2[self]+sum g2[src]) + b2
  k_gemm_mfma<64, 40, 3, 2, 40, _Float16><<<dim3(1536), b256, 0, stream>>>(h1, W2, dinv, g2, N);
  k_agg_v4<40, 5, false, false><<<dim3((N + 15) / 16), b256, 0, stream>>>(
      (const uint4*)g2, offset, ssrc, dinv, b2, out, N);
}

// Round 12
// 249.861 us; speedup vs baseline: 1.2031x; 1.0153x over previous
//
#include <hip/hip_runtime.h>
#include <hip/hip_fp16.h>
#include <cstdint>
#include <cstddef>

#define NPB_SHIFT 8                      // 256 dst-nodes per bucket (r4 empirical best;
#define NPB (1 << NPB_SHIFT)             // 512 was neutral-to-worse, r11)
#define CHUNK 4096                       // edges per partition block (2048 worse, r10)
#define BCAP 6144                        // slots per bucket slab (lambda=4096, +32 sigma)
// nbuck = ceil(N/256) must be <= 512 (N <= 131072) for the LDS arrays below.

typedef _Float16 half8_t __attribute__((ext_vector_type(8)));
typedef _Float16 half4_t __attribute__((ext_vector_type(4)));
typedef _Float16 half2_t __attribute__((ext_vector_type(2)));
typedef float floatx4 __attribute__((ext_vector_type(4)));

#define H2(u) __builtin_bit_cast(half2_t, (u))

// ---------------- graph preprocessing (round-4 exact, proven 251us total) ----
// Banned by measurement: scattered partial-line stores (r5, 3.2x), per-edge
// global atomic histograms (r8, +43us), agg1+gemm2 fusion (r7, -44us occ loss),
// feature-sliced gathers (r9, transaction-bound), CHUNK=2048 (r10), NPB=512 (r11).

__global__ __launch_bounds__(256) void k_partition(const int* __restrict__ src,
                                                   const int* __restrict__ dst,
                                                   int* __restrict__ bfill,
                                                   unsigned* __restrict__ tmp,
                                                   int E, int nbuck) {
  __shared__ int cnt[512];
  __shared__ int lbase[512];
  __shared__ int gdelta[512];
  __shared__ int cur[512];
  __shared__ int ps[256];
  __shared__ unsigned sval[CHUNK];
  __shared__ unsigned short sbid[CHUNK];
  int tid = threadIdx.x;
  int cbase = blockIdx.x * CHUNK;
  for (int i = tid; i < 512; i += 256) cnt[i] = 0;
  __syncthreads();
  int s[16], d[16];
  bool valid[16];
#pragma unroll
  for (int u = 0; u < 16; ++u) {
    int e = cbase + u * 256 + tid;
    valid[u] = e < E;
    s[u] = valid[u] ? src[e] : 0;
    d[u] = valid[u] ? dst[e] : 0;
    if (valid[u]) atomicAdd(&cnt[d[u] >> NPB_SHIFT], 1);
  }
  __syncthreads();
  int c0 = cnt[2 * tid], c1 = cnt[2 * tid + 1];
  int p = c0 + c1;
  ps[tid] = p;
  __syncthreads();
  for (int off = 1; off < 256; off <<= 1) {
    int t = (tid >= off) ? ps[tid - off] : 0;
    __syncthreads();
    ps[tid] += t;
    __syncthreads();
  }
  int ep = ps[tid] - p;                  // exclusive over pairs
  lbase[2 * tid] = ep;
  lbase[2 * tid + 1] = ep + c0;
  __syncthreads();
  for (int i = tid; i < 512; i += 256) {
    cur[i] = lbase[i];
    if (cnt[i]) gdelta[i] = atomicAdd(&bfill[i], cnt[i]) - lbase[i];
  }
  __syncthreads();
#pragma unroll
  for (int u = 0; u < 16; ++u) {
    if (valid[u]) {
      int b = d[u] >> NPB_SHIFT;
      int r = atomicAdd(&cur[b], 1);
      sval[r] = ((unsigned)s[u] << NPB_SHIFT) | (unsigned)(d[u] & (NPB - 1));
      sbid[r] = (unsigned short)b;
    }
  }
  __syncthreads();
  int nv = min(CHUNK, E - cbase);
  for (int i = tid; i < nv; i += 256) {
    unsigned v = sval[i];
    int b = sbid[i];
    tmp[(size_t)b * BCAP + (gdelta[b] + i)] = v;
  }
}

// per bucket: scan all bucket counts in-LDS -> dense base; LDS degree count ->
// dinv + dense offsets; then src-only CSR scatter into dense ssrc.
__global__ __launch_bounds__(256) void k_csr_build(const unsigned* __restrict__ tmp,
                                                   const int* __restrict__ bfill,
                                                   float* __restrict__ dinv,
                                                   int* __restrict__ offset,
                                                   int* __restrict__ ssrc,
                                                   int N, int E, int nbuck) {
  __shared__ int cnt[NPB];
  __shared__ int scan[NPB];
  __shared__ int fillL[NPB];
  __shared__ int bs[512];
  __shared__ int ps[256];
  int b = blockIdx.x, tid = threadIdx.x;
  int nbase = b << NPB_SHIFT;
  int nloc = min(NPB, N - nbase);
  cnt[tid] = 0;
  bs[tid] = (tid < nbuck) ? bfill[tid] : 0;
  bs[tid + 256] = (tid + 256 < nbuck) ? bfill[tid + 256] : 0;
  __syncthreads();
  int c0 = bs[2 * tid], c1 = bs[2 * tid + 1];
  int pp = c0 + c1;
  ps[tid] = pp;
  __syncthreads();
  for (int off = 1; off < 256; off <<= 1) {
    int t = (tid >= off) ? ps[tid - off] : 0;
    __syncthreads();
    ps[tid] += t;
    __syncthreads();
  }
  int ep = ps[tid] - pp;
  bs[2 * tid] = ep;
  bs[2 * tid + 1] = ep + c0;
  __syncthreads();
  int ebeg = bs[b];                    // dense base of this bucket
  int cntB = bfill[b];
  int sbeg = b * BCAP;
  int send = sbeg + cntB;
  for (int j = sbeg + tid; j < send; j += 256) atomicAdd(&cnt[tmp[j] & (NPB - 1)], 1);
  __syncthreads();
  int v = cnt[tid];
  scan[tid] = v;
  __syncthreads();
  for (int off = 1; off < NPB; off <<= 1) {
    int t = (tid >= off) ? scan[tid - off] : 0;
    __syncthreads();
    scan[tid] += t;
    __syncthreads();
  }
  int myoff = ebeg + scan[tid] - v;
  fillL[tid] = myoff;
  if (tid < nloc) {
    offset[nbase + tid] = myoff;
    dinv[nbase + tid] = rsqrtf((float)(v + 1));   // +1 self-loop
  }
  if (b == nbuck - 1 && tid == NPB - 1) offset[N] = ebeg + scan[tid];   // == E
  __syncthreads();
  int j = sbeg + tid;
  for (; j + 3 * 256 < send; j += 4 * 256) {
    unsigned p[4];
#pragma unroll
    for (int u = 0; u < 4; ++u) p[u] = tmp[j + u * 256];
#pragma unroll
    for (int u = 0; u < 4; ++u) {
      int pos = atomicAdd(&fillL[p[u] & (NPB - 1)], 1);
      ssrc[pos] = (int)(p[u] >> NPB_SHIFT);
    }
  }
  for (; j < send; j += 256) {
    unsigned p = tmp[j];
    int pos = atomicAdd(&fillL[p & (NPB - 1)], 1);
    ssrc[pos] = (int)(p >> NPB_SHIFT);
  }
}

// ---------------- dense layers: MFMA 16x16x32 f16, output scaled by dinv ------
// Writes g[node] = dinv[node] * (x @ W)[node] as fp16, row stride OS.
template <int K, int COLS, int MT, int KC, int OS, typename XT>
__global__ __launch_bounds__(256) void k_gemm_mfma(const XT* __restrict__ x,
                                                   const float* __restrict__ W,
                                                   const float* __restrict__ dinv,
                                                   _Float16* __restrict__ out, int n) {
  int lane = threadIdx.x & 63;
  int quad = lane >> 4;
  int l15 = lane & 15;
  int gwave = (blockIdx.x * blockDim.x + threadIdx.x) >> 6;
  int nwave = (gridDim.x * blockDim.x) >> 6;
  int ntiles = (n + 15) >> 4;

  half8_t afrag[MT][KC];
#pragma unroll
  for (int m = 0; m < MT; ++m) {
    int colw = m * 16 + l15;
    if (colw > COLS - 1) colw = COLS - 1;
#pragma unroll
    for (int c = 0; c < KC; ++c) {
#pragma unroll
      for (int j = 0; j < 8; ++j) {
        int kk = c * 32 + quad * 8 + j;
        afrag[m][c][j] = (_Float16)W[kk * COLS + colw];
      }
    }
  }

  for (int tile = gwave; tile < ntiles; tile += nwave) {
    int node0 = tile << 4;
    int nodeB = node0 + l15;
    int nodeC = nodeB < n ? nodeB : n - 1;
    const XT* xr = x + (size_t)nodeC * K;
    float dv = dinv[nodeC];
    half8_t bfrag[KC];
#pragma unroll
    for (int c = 0; c < KC; ++c) {
      if constexpr (sizeof(XT) == 4) {
        float4 lo = *(const float4*)(xr + c * 32 + quad * 8);
        float4 hi = *(const float4*)(xr + c * 32 + quad * 8 + 4);
        bfrag[c][0] = (_Float16)lo.x; bfrag[c][1] = (_Float16)lo.y;
        bfrag[c][2] = (_Float16)lo.z; bfrag[c][3] = (_Float16)lo.w;
        bfrag[c][4] = (_Float16)hi.x; bfrag[c][5] = (_Float16)hi.y;
        bfrag[c][6] = (_Float16)hi.z; bfrag[c][7] = (_Float16)hi.w;
      } else {
        bfrag[c] = *(const half8_t*)(xr + c * 32 + quad * 8);
      }
    }
    floatx4 acc[MT];
#pragma unroll
    for (int m = 0; m < MT; ++m) acc[m] = (floatx4){0.f, 0.f, 0.f, 0.f};
#pragma unroll
    for (int c = 0; c < KC; ++c)
#pragma unroll
      for (int m = 0; m < MT; ++m)
        acc[m] = __builtin_amdgcn_mfma_f32_16x16x32_f16(afrag[m][c], bfrag[c], acc[m], 0, 0, 0);

    if (nodeB < n) {
#pragma unroll
      for (int m = 0; m < MT; ++m) {
        int colBase = m * 16 + quad * 4;
        if (colBase < COLS) {
          half4_t hv = {(_Float16)(acc[m][0] * dv), (_Float16)(acc[m][1] * dv),
                        (_Float16)(acc[m][2] * dv), (_Float16)(acc[m][3] * dv)};
          *(half4_t*)(out + (size_t)nodeB * OS + colBase) = hv;
        }
      }
    }
  }
}

// ---------------- aggregation: 4 nodes per wave, 8 gathers in flight ----------
// Fill-limited at the random-128B-line wall (~2.26 TB/s, 91MB = 12.8MB x
// 8 XCDs x (1-e^-2)). Measured: more MLP = 0 (r2); less occupancy = much
// worse (r7); feature-slicing = transaction-bound, worse (r9). Do not
// restructure.

__device__ __forceinline__ void addacc(half2_t* acc, uint4 r) {
  acc[0] += H2(r.x); acc[1] += H2(r.y); acc[2] += H2(r.z); acc[3] += H2(r.w);
}

template <int F, int S8, bool RELU, bool OUT_HALF>
__global__ __launch_bounds__(256) void k_agg_v4(const uint4* __restrict__ g8,
                                                const int* __restrict__ offset,
                                                const int* __restrict__ ssrc,
                                                const float* __restrict__ dinv,
                                                const float* __restrict__ bias,
                                                void* __restrict__ outp, int n) {
  constexpr int F8 = F / 8;            // used octets per row (8 or 5)
  int lane = threadIdx.x & 63;
  int g = lane >> 3;                   // edge group 0..7
  int t = lane & 7;                    // feature octet
  int wave = (blockIdx.x * blockDim.x + threadIdx.x) >> 6;
  int nb = wave * 4;                   // first node of this wave
  if (nb >= n) return;
  bool tv = t < F8;

  uint4 sv[4];
#pragma unroll
  for (int w = 0; w < 4; ++w) {
    int node = nb + w;
    int nc = node < n ? node : n - 1;
    sv[w] = (tv && g == 0 && node < n) ? g8[(size_t)nc * S8 + t]
                                       : make_uint4(0, 0, 0, 0);
  }

  int jj[4], ee[4];
  float di[4];
#pragma unroll
  for (int w = 0; w < 4; ++w) {
    int node = nb + w;
    bool nv = node < n;
    int nc = nv ? node : n - 1;
    int b0 = offset[nc];
    int b1 = offset[nc + 1];
    jj[w] = b0;
    ee[w] = nv ? b1 : b0;
    di[w] = dinv[nc];
  }

  half2_t acc[4][4];
#pragma unroll
  for (int w = 0; w < 4; ++w) {
#pragma unroll
    for (int k = 0; k < 4; ++k) acc[w][k] = H2(0u);
    addacc(acc[w], sv[w]);
  }

  for (;;) {
    bool a0[4], a1[4];
    bool any = false;
#pragma unroll
    for (int w = 0; w < 4; ++w) {
      a0[w] = jj[w] + 8 <= ee[w];
      a1[w] = jj[w] + 16 <= ee[w];
      any = any || a0[w];
    }
    if (!any) break;
    int s0[4], s1[4];
#pragma unroll
    for (int w = 0; w < 4; ++w) {
      s0[w] = a0[w] ? ssrc[jj[w] + g] : 0;
      s1[w] = a1[w] ? ssrc[jj[w] + 8 + g] : 0;
    }
    uint4 r0[4], r1[4];
#pragma unroll
    for (int w = 0; w < 4; ++w) {
      r0[w] = (a0[w] && tv) ? g8[(size_t)s0[w] * S8 + t] : make_uint4(0, 0, 0, 0);
      r1[w] = (a1[w] && tv) ? g8[(size_t)s1[w] * S8 + t] : make_uint4(0, 0, 0, 0);
    }
#pragma unroll
    for (int w = 0; w < 4; ++w) {
      addacc(acc[w], r0[w]);
      addacc(acc[w], r1[w]);
      jj[w] += a1[w] ? 16 : (a0[w] ? 8 : 0);
    }
  }

  {
    int rem[4];
    uint4 rv[4];
#pragma unroll
    for (int w = 0; w < 4; ++w) {
      rem[w] = ee[w] - jj[w];
      int gi = (g < rem[w]) ? g : (rem[w] - 1);
      int sW = rem[w] > 0 ? ssrc[jj[w] + gi] : 0;
      rv[w] = (tv && g < rem[w]) ? g8[(size_t)sW * S8 + t] : make_uint4(0, 0, 0, 0);
    }
#pragma unroll
    for (int w = 0; w < 4; ++w) addacc(acc[w], rv[w]);
  }

#pragma unroll
  for (int w = 0; w < 4; ++w) {
#pragma unroll
    for (int k = 0; k < 4; ++k) {
      int u = __builtin_bit_cast(int, acc[w][k]);
      acc[w][k] += H2((unsigned)__shfl_xor(u, 8));
      u = __builtin_bit_cast(int, acc[w][k]);
      acc[w][k] += H2((unsigned)__shfl_xor(u, 16));
      u = __builtin_bit_cast(int, acc[w][k]);
      acc[w][k] += H2((unsigned)__shfl_xor(u, 32));
    }
    int node = nb + w;
    if (node < n && lane < F8) {
      float f[8];
#pragma unroll
      for (int k = 0; k < 4; ++k) {
        f[2 * k] = (float)acc[w][k][0];
        f[2 * k + 1] = (float)acc[w][k][1];
      }
      const float* bb = bias + lane * 8;
      float o[8];
#pragma unroll
      for (int j = 0; j < 8; ++j) {
        o[j] = fmaf(f[j], di[w], bb[j]);
        if (RELU) o[j] = fmaxf(o[j], 0.f);
      }
      if (OUT_HALF) {
        _Float16* op = (_Float16*)outp + (size_t)node * F + lane * 8;
        half2_t p0 = {(_Float16)o[0], (_Float16)o[1]};
        half2_t p1 = {(_Float16)o[2], (_Float16)o[3]};
        half2_t p2 = {(_Float16)o[4], (_Float16)o[5]};
        half2_t p3 = {(_Float16)o[6], (_Float16)o[7]};
        uint4 wv;
        wv.x = __builtin_bit_cast(unsigned, p0);
        wv.y = __builtin_bit_cast(unsigned, p1);
        wv.z = __builtin_bit_cast(unsigned, p2);
        wv.w = __builtin_bit_cast(unsigned, p3);
        *(uint4*)op = wv;
      } else {
        float* op = (float*)outp + (size_t)node * F + lane * 8;
        *(float4*)op = make_float4(o[0], o[1], o[2], o[3]);
        *(float4*)(op + 4) = make_float4(o[4], o[5], o[6], o[7]);
      }
    }
  }
}

// ---------------- launch ----------------

extern "C" void kernel_launch(void* const* d_in, const int* in_sizes, int n_in,
                              void* d_out, int out_size, void* d_ws, size_t ws_size,
                              hipStream_t stream) {
  const float* x  = (const float*)d_in[0];
  const int*   ei = (const int*)d_in[1];
  const float* W1 = (const float*)d_in[2];
  const float* b1 = (const float*)d_in[3];
  const float* W2 = (const float*)d_in[4];
  const float* b2 = (const float*)d_in[5];
  float* out = (float*)d_out;

  const int F_IN = 128, HID = 64, C = 40;
  int N = in_sizes[0] / F_IN;
  int E = in_sizes[1] / 2;
  const int* src = ei;
  const int* dst = ei + E;
  int nbuck = (N + NPB - 1) >> NPB_SHIFT;   // 391 for N=100000

  char* w = (char*)d_ws;
  size_t o = 0;
  auto alloc = [&](size_t bytes) -> void* {
    void* p = w + o;
    o = (o + bytes + 255) & ~(size_t)255;
    return p;
  };
  float*    dinv   = (float*)alloc((size_t)N * 4);
  int*      offset = (int*)alloc((size_t)(N + 1) * 4);
  int*      bfill  = (int*)alloc(512 * 4);
  unsigned* tmp    = (unsigned*)alloc((size_t)nbuck * BCAP * 4);
  int*      ssrc   = (int*)alloc((size_t)E * 4);
  _Float16* g1     = (_Float16*)alloc((size_t)N * HID * 2);   // dinv*(xW1), stride 64
  _Float16* h1     = (_Float16*)alloc((size_t)N * HID * 2);   // relu layer-1 out, fp16
  _Float16* g2     = (_Float16*)alloc((size_t)N * C * 2);     // dinv*(h1W2), stride 40

  dim3 b256(256);

  // partition into per-bucket slabs + dense CSR compaction
  hipMemsetAsync(bfill, 0, 512 * 4, stream);
  k_partition<<<dim3((E + CHUNK - 1) / CHUNK), b256, 0, stream>>>(src, dst, bfill, tmp, E, nbuck);
  k_csr_build<<<dim3(nbuck), b256, 0, stream>>>(tmp, bfill, dinv, offset, ssrc, N, E, nbuck);

  // layer 1: g1 = dinv * (x @ W1);  h1 = relu(dinv*(g1[self]+sum g1[src]) + b1)
  k_gemm_mfma<128, 64, 4, 4, 64, float><<<dim3(1536), b256, 0, stream>>>(x, W1, dinv, g1, N);
  k_agg_v4<64, 8, true, true><<<dim3((N + 15) / 16), b256, 0, stream>>>(
      (const uint4*)g1, offset, ssrc, dinv, b1, h1, N);

  // layer 2: g2 = dinv * (h1 @ W2); out = dinv*(g2[self]+sum g2[src]) + b2
  k_gemm_mfma<64, 40, 3, 2, 40, _Float16><<<dim3(1536), b256, 0, stream>>>(h1, W2, dinv, g2, N);
  k_agg_v4<40, 5, false, false><<<dim3((N + 15) / 16), b256, 0, stream>>>(
      (const uint4*)g2, offset, ssrc, dinv, b2, out, N);
}